// Round 4
// baseline (10778.001 us; speedup 1.0000x reference)
//
#include <hip/hip_runtime.h>
#include <math.h>

#define BB 64
#define DD 128
#define NN 400
#define MM 50
#define HH 8
#define KDIM 16
#define NC 4
#define KW 7

#define SZ_C (BB * DD * NN)   // 3,276,800
#define SZ_Q (BB * DD * MM)   //   409,600
#define SSTAT (BB * NN + BB * MM)  // 28,800; q stats at offset BB*NN

// ---------------- canonical weight transpose: Wcan[m][d][e] ----------------
__global__ void k_transposeW(const float* __restrict__ pw_w, const float* __restrict__ Wo,
                             const float* __restrict__ Wfc, const float* __restrict__ Wq,
                             const float* __restrict__ Wk, const float* __restrict__ Wv,
                             float* __restrict__ Wcan) {
  int idx = blockIdx.x * 256 + threadIdx.x;
  if (idx >= 9 * 16384) return;
  int m = idx >> 14;
  int r = idx & 16383;
  int d = r >> 7, e = r & 127;
  float v;
  if (m < 4) v = pw_w[m * 16384 + e * 128 + d];
  else if (m == 4) v = Wo[d * 128 + e];
  else if (m == 5) v = Wfc[e * 128 + d];
  else {
    const float* W = (m == 6) ? Wq : (m == 7) ? Wk : Wv;
    v = W[((e >> 4) * 128 + d) * 16 + (e & 15)];
  }
  Wcan[idx] = v;
}

// ---------------- fused PE add + LN stats ----------------
// blocks 0..447: ctx (b=blk/7, l0=(blk%7)*64); 448..511: q (b=blk-448)
__global__ void k_pestats(const float* __restrict__ xC, const float* __restrict__ xQ,
                          float* __restrict__ yC, float* __restrict__ yQ,
                          float* __restrict__ mu, float* __restrict__ inv) {
  int blk = blockIdx.x;
  const float* x; float* y; int L, l0, b, soff;
  if (blk < 448) { b = blk / 7; l0 = (blk % 7) * 64; x = xC; y = yC; L = NN; soff = 0; }
  else { b = blk - 448; l0 = 0; x = xQ; y = yQ; L = MM; soff = BB * NN; }
  int tid = threadIdx.x;
  int ll = tid & 63;
  int dq = tid >> 6;
  int l = l0 + ll;
  __shared__ float s_sum[4][64], s_sq[4][64];
  float sum = 0.f, sq = 0.f;
  if (l < L) {
    const float* px = x + (size_t)b * DD * L + l;
    float* py = y + (size_t)b * DD * L + l;
    for (int d = dq * 32; d < dq * 32 + 32; ++d) {
      int de = d & ~1;
      float freq = __expf((float)de * (-9.210340371976184f / 128.0f));
      float ph = (d & 1) ? 1.5707963267948966f : 0.0f;
      float v = px[(size_t)d * L] + sinf((float)l * freq + ph);
      py[(size_t)d * L] = v;
      sum += v; sq += v * v;
    }
  }
  s_sum[dq][ll] = sum; s_sq[dq][ll] = sq;
  __syncthreads();
  if (dq == 0 && l < L) {
    float ts = s_sum[0][ll] + s_sum[1][ll] + s_sum[2][ll] + s_sum[3][ll];
    float tq = s_sq[0][ll] + s_sq[1][ll] + s_sq[2][ll] + s_sq[3][ll];
    float m = ts * (1.0f / 128.0f);
    float var = (tq - 128.0f * m * m) * (1.0f / 127.0f);
    float sd = sqrtf(fmaxf(var, 0.f));
    mu[soff + b * L + l] = m;
    inv[soff + b * L + l] = 1.0f / (sd + 1e-6f);
  }
}

// ---------------- fused conv layer, 64-col tiles (512 blocks = 2/CU) ----------------
// LN + depthwise K=7 during X staging + 128x(64) pointwise GEMM + relu + residual
// + LN-stats epilogue for the next layer.
__global__ __launch_bounds__(256) void k_convgemm(
    const float* __restrict__ xC, const float* __restrict__ xQ,
    float* __restrict__ outC, float* __restrict__ outQ,
    const float* __restrict__ Wc, const float* __restrict__ pwb,
    const float* __restrict__ dww, const float* __restrict__ dwb,
    const float* __restrict__ muI, const float* __restrict__ invI,
    float* __restrict__ muO, float* __restrict__ invO,
    const float* __restrict__ g, const float* __restrict__ beta) {
  int blk = blockIdx.x;
  int b = blk >> 3, tile = blk & 7;
  const float* x; float* out; int L, l0, soff;
  if (tile < 7) { x = xC; out = outC; L = NN; l0 = tile * 64; soff = 0; }
  else { x = xQ; out = outQ; L = MM; l0 = 0; soff = BB * NN; }
  __shared__ float Wl[32 * 128];
  __shared__ float Xl[32 * 64];
  __shared__ float Sm[74], Si[74];   // stats halo [l0-4, l0+70)
  int tid = threadIdx.x;
  const float* xb = x + (size_t)b * DD * L;
  for (int t = tid; t < 74; t += 256) {
    int gl = l0 + t - 4;
    bool ok = (gl >= 0 && gl < L);
    Sm[t] = ok ? muI[soff + b * L + gl] : 0.f;
    Si[t] = ok ? invI[soff + b * L + gl] : 0.f;
  }
  float acc[8][4];
  #pragma unroll
  for (int i = 0; i < 8; ++i)
    #pragma unroll
    for (int j = 0; j < 4; ++j) acc[i][j] = 0.f;
  __syncthreads();
  int kk = tid >> 3;          // staging row 0..31
  int c0 = (tid & 7) * 8;     // staging col base 0..56
  for (int kc = 0; kc < 4; ++kc) {
    int d0 = kc * 32;
    // W staging (float4)
    #pragma unroll
    for (int i = 0; i < 4; ++i) {
      int idx = i * 256 + tid;                 // 0..1023 float4
      ((float4*)Wl)[idx] = ((const float4*)Wc)[(size_t)d0 * 32 + idx];
    }
    // X staging: LN + depthwise conv; 8 outputs per thread
    {
      int d = d0 + kk;
      const float* xrow = xb + (size_t)d * L;
      float gd = g[d], bd = beta[d];
      float wv[7];
      #pragma unroll
      for (int u = 0; u < 7; ++u) wv[u] = dww[d * 7 + u];
      float dbv = dwb[d];
      float xw[14];
      int gbase = l0 + c0 - 3;   // xw[s] = LN'd x at gbase+s, s in [0,14)
      int lb = gbase - 1;        // 16-value load window
      if (lb >= 0 && lb + 16 <= L && (((d * L + lb) & 3) == 0)) {
        const float4* p = (const float4*)&xrow[lb];
        float4 A = p[0], B = p[1], C = p[2], D = p[3];
        float xr[16] = {A.x, A.y, A.z, A.w, B.x, B.y, B.z, B.w,
                        C.x, C.y, C.z, C.w, D.x, D.y, D.z, D.w};
        #pragma unroll
        for (int s = 0; s < 14; ++s)
          xw[s] = gd * (xr[s + 1] - Sm[c0 + 1 + s]) * Si[c0 + 1 + s] + bd;
      } else {
        #pragma unroll
        for (int s = 0; s < 14; ++s) {
          int gl = gbase + s;
          float v = 0.f;   // zero-pad AFTER LN
          if (gl >= 0 && gl < L)
            v = gd * (xrow[gl] - Sm[c0 + 1 + s]) * Si[c0 + 1 + s] + bd;
          xw[s] = v;
        }
      }
      float o[8];
      #pragma unroll
      for (int c = 0; c < 8; ++c) {
        float a = dbv;
        #pragma unroll
        for (int u = 0; u < 7; ++u) a += wv[u] * xw[c + u];
        o[c] = a;
      }
      float4 o0 = {o[0], o[1], o[2], o[3]};
      float4 o1 = {o[4], o[5], o[6], o[7]};
      *(float4*)&Xl[kk * 64 + c0] = o0;
      *(float4*)&Xl[kk * 64 + c0 + 4] = o1;
    }
    __syncthreads();
    int e0 = (tid >> 4) * 8, cq = (tid & 15) * 4;
    for (int k = 0; k < 32; ++k) {
      const float4* wp = (const float4*)&Wl[k * 128 + e0];
      float4 w0 = wp[0], w1 = wp[1];
      float4 xv = *(const float4*)&Xl[k * 64 + cq];
      float we[8] = {w0.x, w0.y, w0.z, w0.w, w1.x, w1.y, w1.z, w1.w};
      float xe[4] = {xv.x, xv.y, xv.z, xv.w};
      #pragma unroll
      for (int i = 0; i < 8; ++i)
        #pragma unroll
        for (int j = 0; j < 4; ++j) acc[i][j] += we[i] * xe[j];
    }
    __syncthreads();
  }
  // epilogue: relu + residual + per-column stats
  int e0 = (tid >> 4) * 8, cq = (tid & 15) * 4;
  float ssum[4], ssq[4];
  #pragma unroll
  for (int j = 0; j < 4; ++j) { ssum[j] = 0.f; ssq[j] = 0.f; }
  #pragma unroll
  for (int i = 0; i < 8; ++i) {
    float bi = pwb[e0 + i];
    float* po = out + ((size_t)b * DD + e0 + i) * L;
    const float* pr = xb + (size_t)(e0 + i) * L;
    #pragma unroll
    for (int j = 0; j < 4; ++j) {
      int l = l0 + cq + j;
      if (l < L) {
        float v = fmaxf(acc[i][j] + bi, 0.f) + pr[l];
        po[l] = v;
        ssum[j] += v; ssq[j] += v * v;
      }
    }
  }
  int grp = tid >> 4;
  #pragma unroll
  for (int j = 0; j < 4; ++j) {
    Xl[grp * 64 + cq + j] = ssum[j];
    Wl[grp * 64 + cq + j] = ssq[j];
  }
  __syncthreads();
  if (tid < 64) {
    int l = l0 + tid;
    if (l < L) {
      float ts = 0.f, tq = 0.f;
      #pragma unroll
      for (int gg = 0; gg < 16; ++gg) { ts += Xl[gg * 64 + tid]; tq += Wl[gg * 64 + tid]; }
      float m = ts * (1.0f / 128.0f);
      float var = (tq - 128.0f * m * m) * (1.0f / 127.0f);
      float sd = sqrtf(fmaxf(var, 0.f));
      muO[soff + b * L + l] = m;
      invO[soff + b * L + l] = 1.0f / (sd + 1e-6f);
    }
  }
}

// ---------------- 128x64 GEMM tiles, 512 blocks ----------------
// LNF: LN during staging. ACT: 0=write, 1=+residual. STATS: write muO/invO of result.
template <int LNF, int ACT, int STATS>
__global__ __launch_bounds__(256) void k_gemm64(
    const float* __restrict__ xC, const float* __restrict__ xQ,
    float* __restrict__ outC, float* __restrict__ outQ,
    const float* __restrict__ Wc, const float* __restrict__ bias,
    const float* __restrict__ mu, const float* __restrict__ inv,
    float* __restrict__ muO, float* __restrict__ invO,
    const float* __restrict__ g, const float* __restrict__ beta) {
  int blk = blockIdx.x;
  int b = blk >> 3, tile = blk & 7;
  const float* x; float* out; int L, l0, soff;
  if (tile < 7) { x = xC; out = outC; L = NN; l0 = tile * 64; soff = 0; }
  else { x = xQ; out = outQ; L = MM; l0 = 0; soff = BB * NN; }
  __shared__ float Wl[32 * 128];
  __shared__ float Xl[32 * 64];
  int tid = threadIdx.x;
  float acc[8][4];
  #pragma unroll
  for (int i = 0; i < 8; ++i)
    #pragma unroll
    for (int j = 0; j < 4; ++j) acc[i][j] = 0.f;
  const float* xb = x + (size_t)b * DD * L;
  const float* pmu = mu + soff + b * L;
  const float* pin = inv + soff + b * L;
  for (int kc = 0; kc < 4; ++kc) {
    int d0 = kc * 32;
    #pragma unroll
    for (int i = 0; i < 4; ++i) {
      int idx = i * 256 + tid;
      ((float4*)Wl)[idx] = ((const float4*)Wc)[(size_t)d0 * 32 + idx];
    }
    #pragma unroll
    for (int t = 0; t < 8; ++t) {
      int idx = t * 256 + tid;
      int k = idx >> 6, l = idx & 63;
      float v = 0.f;
      int gl = l0 + l;
      if (gl < L) {
        v = xb[(size_t)(d0 + k) * L + gl];
        if (LNF) v = g[d0 + k] * (v - pmu[gl]) * pin[gl] + beta[d0 + k];
      }
      Xl[idx] = v;
    }
    __syncthreads();
    int e0 = (tid >> 4) * 8, cq = (tid & 15) * 4;
    for (int k = 0; k < 32; ++k) {
      const float4* wp = (const float4*)&Wl[k * 128 + e0];
      float4 w0 = wp[0], w1 = wp[1];
      float4 xv = *(const float4*)&Xl[k * 64 + cq];
      float we[8] = {w0.x, w0.y, w0.z, w0.w, w1.x, w1.y, w1.z, w1.w};
      float xe[4] = {xv.x, xv.y, xv.z, xv.w};
      #pragma unroll
      for (int i = 0; i < 8; ++i)
        #pragma unroll
        for (int j = 0; j < 4; ++j) acc[i][j] += we[i] * xe[j];
    }
    __syncthreads();
  }
  int e0 = (tid >> 4) * 8, cq = (tid & 15) * 4;
  float ssum[4], ssq[4];
  #pragma unroll
  for (int j = 0; j < 4; ++j) { ssum[j] = 0.f; ssq[j] = 0.f; }
  #pragma unroll
  for (int i = 0; i < 8; ++i) {
    float bi = bias[e0 + i];
    float* po = out + ((size_t)b * DD + e0 + i) * L;
    #pragma unroll
    for (int j = 0; j < 4; ++j) {
      int l = l0 + cq + j;
      if (l < L) {
        float v = acc[i][j] + bi;
        if (ACT != 0) v += po[l];
        po[l] = v;
        if (STATS) { ssum[j] += v; ssq[j] += v * v; }
      }
    }
  }
  if (STATS) {
    int grp = tid >> 4;
    #pragma unroll
    for (int j = 0; j < 4; ++j) {
      Xl[grp * 64 + cq + j] = ssum[j];
      Wl[grp * 64 + cq + j] = ssq[j];
    }
    __syncthreads();
    if (tid < 64) {
      int l = l0 + tid;
      if (l < L) {
        float ts = 0.f, tq = 0.f;
        #pragma unroll
        for (int gg = 0; gg < 16; ++gg) { ts += Xl[gg * 64 + tid]; tq += Wl[gg * 64 + tid]; }
        float m = ts * (1.0f / 128.0f);
        float var = (tq - 128.0f * m * m) * (1.0f / 127.0f);
        float sd = sqrtf(fmaxf(var, 0.f));
        muO[soff + b * L + l] = m;
        invO[soff + b * L + l] = 1.0f / (sd + 1e-6f);
      }
    }
  }
}

// ---------------- fused QKV GEMM: 3 x 512 blocks ----------------
__global__ __launch_bounds__(256) void k_gemm_qkv(
    const float* __restrict__ xC, const float* __restrict__ xQ,
    float* __restrict__ o1C, float* __restrict__ o1Q,
    float* __restrict__ o2C, float* __restrict__ o2Q,
    float* __restrict__ o3C, float* __restrict__ o3Q,
    const float* __restrict__ Wcan,
    const float* __restrict__ bq, const float* __restrict__ bk, const float* __restrict__ bv,
    const float* __restrict__ mu, const float* __restrict__ inv,
    const float* __restrict__ g, const float* __restrict__ beta) {
  int blk0 = blockIdx.x;
  int grp = blk0 >> 9;
  int blk = blk0 & 511;
  const float* Wc = Wcan + (size_t)(6 + grp) * 16384;
  const float* bias = (grp == 0) ? bq : (grp == 1) ? bk : bv;
  float* oC = (grp == 0) ? o1C : (grp == 1) ? o2C : o3C;
  float* oQ = (grp == 0) ? o1Q : (grp == 1) ? o2Q : o3Q;
  int b = blk >> 3, tile = blk & 7;
  const float* x; float* out; int L, l0, soff;
  if (tile < 7) { x = xC; out = oC; L = NN; l0 = tile * 64; soff = 0; }
  else { x = xQ; out = oQ; L = MM; l0 = 0; soff = BB * NN; }
  __shared__ float Wl[32 * 128];
  __shared__ float Xl[32 * 64];
  int tid = threadIdx.x;
  float acc[8][4];
  #pragma unroll
  for (int i = 0; i < 8; ++i)
    #pragma unroll
    for (int j = 0; j < 4; ++j) acc[i][j] = 0.f;
  const float* xb = x + (size_t)b * DD * L;
  const float* pmu = mu + soff + b * L;
  const float* pin = inv + soff + b * L;
  for (int kc = 0; kc < 4; ++kc) {
    int d0 = kc * 32;
    #pragma unroll
    for (int i = 0; i < 4; ++i) {
      int idx = i * 256 + tid;
      ((float4*)Wl)[idx] = ((const float4*)Wc)[(size_t)d0 * 32 + idx];
    }
    #pragma unroll
    for (int t = 0; t < 8; ++t) {
      int idx = t * 256 + tid;
      int k = idx >> 6, l = idx & 63;
      float v = 0.f;
      int gl = l0 + l;
      if (gl < L) {
        v = xb[(size_t)(d0 + k) * L + gl];
        v = g[d0 + k] * (v - pmu[gl]) * pin[gl] + beta[d0 + k];
      }
      Xl[idx] = v;
    }
    __syncthreads();
    int e0 = (tid >> 4) * 8, cq = (tid & 15) * 4;
    for (int k = 0; k < 32; ++k) {
      const float4* wp = (const float4*)&Wl[k * 128 + e0];
      float4 w0 = wp[0], w1 = wp[1];
      float4 xv = *(const float4*)&Xl[k * 64 + cq];
      float we[8] = {w0.x, w0.y, w0.z, w0.w, w1.x, w1.y, w1.z, w1.w};
      float xe[4] = {xv.x, xv.y, xv.z, xv.w};
      #pragma unroll
      for (int i = 0; i < 8; ++i)
        #pragma unroll
        for (int j = 0; j < 4; ++j) acc[i][j] += we[i] * xe[j];
    }
    __syncthreads();
  }
  int e0 = (tid >> 4) * 8, cq = (tid & 15) * 4;
  #pragma unroll
  for (int i = 0; i < 8; ++i) {
    float bi = bias[e0 + i];
    float* po = out + ((size_t)b * DD + e0 + i) * L;
    #pragma unroll
    for (int j = 0; j < 4; ++j) {
      int l = l0 + cq + j;
      if (l < L) po[l] = acc[i][j] + bi;
    }
  }
}

// ---------------- attention (unchanged from R3) ----------------
__global__ __launch_bounds__(256) void k_attn2(
    const float* __restrict__ qC, const float* __restrict__ kC, const float* __restrict__ vC,
    const float* __restrict__ qQ, const float* __restrict__ kQ, const float* __restrict__ vQ,
    const float* __restrict__ cmask, const float* __restrict__ qmask,
    float* __restrict__ oC, float* __restrict__ oQ) {
  int blk = blockIdx.x;
  const float *qp, *kp, *vp, *mk; float* op; int L, b, h, q0, qcnt;
  if (blk < 1024) {
    b = blk >> 4; h = (blk >> 1) & 7; int half = blk & 1;
    qp = qC; kp = kC; vp = vC; mk = cmask; op = oC; L = NN;
    q0 = half * 256; qcnt = half ? (NN - 256) : 256;
  } else {
    int bb = blk - 1024; b = bb >> 3; h = bb & 7;
    qp = qQ; kp = kQ; vp = vQ; mk = qmask; op = oQ; L = MM;
    q0 = 0; qcnt = MM;
  }
  __shared__ float Kl[NN * KDIM];
  __shared__ float Vl[NN * KDIM];
  __shared__ float Ml[NN];
  int tid = threadIdx.x;
  size_t base = ((size_t)b * DD + h * KDIM) * L;
  int KP = (L + 7) & ~7;
  for (int idx = tid; idx < KDIM * L; idx += 256) {
    int t = idx / L, j = idx - t * L;
    Kl[j * KDIM + t] = kp[base + (size_t)t * L + j];
    Vl[j * KDIM + t] = vp[base + (size_t)t * L + j];
  }
  for (int idx = tid; idx < (KP - L) * KDIM; idx += 256) {
    int j = L + (idx >> 4), t = idx & 15;
    Kl[j * KDIM + t] = 0.f; Vl[j * KDIM + t] = 0.f;
  }
  for (int j = tid; j < KP; j += 256)
    Ml[j] = (j < L) ? -1e30f * (1.0f - mk[b * L + j]) : -1e30f;
  __syncthreads();
  if (tid >= qcnt) return;

  int i = q0 + tid;
  float q[KDIM];
  #pragma unroll
  for (int t = 0; t < KDIM; ++t) q[t] = qp[base + (size_t)t * L + i] * 0.25f;
  float m = -1e30f, ls = 0.f;
  float acc[KDIM];
  #pragma unroll
  for (int t = 0; t < KDIM; ++t) acc[t] = 0.f;
  for (int j0 = 0; j0 < KP; j0 += 8) {
    const float4* mp = (const float4*)&Ml[j0];
    float4 ma0 = mp[0], ma1 = mp[1];
    float mav[8] = {ma0.x, ma0.y, ma0.z, ma0.w, ma1.x, ma1.y, ma1.z, ma1.w};
    float s[8];
    #pragma unroll
    for (int jj = 0; jj < 8; ++jj) {
      const float4* kf = (const float4*)&Kl[(j0 + jj) * KDIM];
      float4 k0 = kf[0], k1 = kf[1], k2 = kf[2], k3 = kf[3];
      float da = q[0] * k0.x + q[1] * k0.y + q[2] * k0.z + q[3] * k0.w
               + q[4] * k1.x + q[5] * k1.y + q[6] * k1.z + q[7] * k1.w;
      float db = q[8] * k2.x + q[9] * k2.y + q[10] * k2.z + q[11] * k2.w
               + q[12] * k3.x + q[13] * k3.y + q[14] * k3.z + q[15] * k3.w;
      s[jj] = da + db + mav[jj];
    }
    float cm = s[0];
    #pragma unroll
    for (int jj = 1; jj < 8; ++jj) cm = fmaxf(cm, s[jj]);
    if (cm > m) {
      float sc = __expf(m - cm);
      ls *= sc;
      #pragma unroll
      for (int t = 0; t < KDIM; ++t) acc[t] *= sc;
      m = cm;
    }
    #pragma unroll
    for (int jj = 0; jj < 8; ++jj) {
      float p = __expf(s[jj] - m);
      ls += p;
      const float4* vf = (const float4*)&Vl[(j0 + jj) * KDIM];
      float4 v0 = vf[0], v1 = vf[1], v2 = vf[2], v3 = vf[3];
      acc[0] += p * v0.x;  acc[1] += p * v0.y;  acc[2] += p * v0.z;  acc[3] += p * v0.w;
      acc[4] += p * v1.x;  acc[5] += p * v1.y;  acc[6] += p * v1.z;  acc[7] += p * v1.w;
      acc[8] += p * v2.x;  acc[9] += p * v2.y;  acc[10] += p * v2.z; acc[11] += p * v2.w;
      acc[12] += p * v3.x; acc[13] += p * v3.y; acc[14] += p * v3.z; acc[15] += p * v3.w;
    }
  }
  float invl = 1.0f / ls;
  #pragma unroll
  for (int t = 0; t < KDIM; ++t)
    op[base + (size_t)t * L + i] = acc[t] * invl;
}

// ---------------- fused prep: tiled transposes + dotD ----------------
__global__ void k_prep(const float* __restrict__ Cb, const float* __restrict__ Qb,
                       float* __restrict__ C2, float* __restrict__ Q2,
                       const float* __restrict__ wc, const float* __restrict__ wq,
                       float* __restrict__ cd, float* __restrict__ qd) {
  int blk = blockIdx.x, tid = threadIdx.x;
  if (blk < 3840) {
    const float* X; float* Y; int L, rem;
    if (blk < 3328) { X = Cb; Y = C2; L = NN; rem = blk; }
    else { X = Qb; Y = Q2; L = MM; rem = blk - 3328; }
    int ntl = (L + 31) / 32;
    int b = rem / (4 * ntl);
    int r2 = rem % (4 * ntl);
    int d0 = (r2 / ntl) * 32;
    int l0 = (r2 % ntl) * 32;
    __shared__ float T[32][33];
    int c = tid & 31, r8 = tid >> 5;
    const float* xb = X + (size_t)b * DD * L;
    #pragma unroll
    for (int k = 0; k < 4; ++k) {
      int r = r8 + k * 8;
      int l = l0 + c;
      T[r][c] = (l < L) ? xb[(size_t)(d0 + r) * L + l] : 0.f;
    }
    __syncthreads();
    float* yb = Y + (size_t)b * L * DD;
    #pragma unroll
    for (int k = 0; k < 4; ++k) {
      int rr = r8 + k * 8;
      int l = l0 + rr;
      if (l < L) yb[(size_t)l * DD + d0 + c] = T[c][rr];
    }
  } else if (blk < 3940) {
    int idx = (blk - 3840) * 256 + tid;
    if (idx < BB * NN) {
      int l = idx % NN, b = idx / NN;
      const float* px = Cb + (size_t)b * DD * NN + l;
      float acc = 0.f;
      for (int d = 0; d < DD; ++d) acc += px[(size_t)d * NN] * wc[d];
      cd[idx] = acc;
    }
  } else {
    int idx = (blk - 3940) * 256 + tid;
    if (idx < BB * MM) {
      int l = idx % MM, b = idx / MM;
      const float* px = Qb + (size_t)b * DD * MM + l;
      float acc = 0.f;
      for (int d = 0; d < DD; ++d) acc += px[(size_t)d * MM] * wq[d];
      qd[idx] = acc;
    }
  }
}

// ---------------- S[b,n,m] trilinear ----------------
__global__ void k_S(const float* __restrict__ C2, const float* __restrict__ Q2,
                    const float* __restrict__ cd, const float* __restrict__ qd,
                    const float* __restrict__ wm, const float* __restrict__ bias,
                    float* __restrict__ S) {
  int idx = blockIdx.x * 256 + threadIdx.x;
  if (idx >= BB * NN * MM) return;
  int mcol = idx % MM;
  int n = (idx / MM) % NN;
  int b = idx / (MM * NN);
  const float4* pc = (const float4*)(C2 + ((size_t)b * NN + n) * DD);
  const float4* pq = (const float4*)(Q2 + ((size_t)b * MM + mcol) * DD);
  const float4* pw = (const float4*)wm;
  float a0 = 0.f, a1 = 0.f;
  #pragma unroll 4
  for (int d4 = 0; d4 < 32; d4 += 2) {
    float4 c0 = pc[d4], w0 = pw[d4], q0 = pq[d4];
    float4 c1 = pc[d4 + 1], w1 = pw[d4 + 1], q1 = pq[d4 + 1];
    a0 += (c0.x * w0.x) * q0.x + (c0.y * w0.y) * q0.y + (c0.z * w0.z) * q0.z + (c0.w * w0.w) * q0.w;
    a1 += (c1.x * w1.x) * q1.x + (c1.y * w1.y) * q1.y + (c1.z * w1.z) * q1.z + (c1.w * w1.w) * q1.w;
  }
  S[idx] = a0 + a1 + cd[b * NN + n] + qd[b * MM + mcol] + bias[0];
}

// ---------------- merged softmaxes ----------------
__global__ void k_smax(const float* __restrict__ S, float* __restrict__ Sr,
                       float* __restrict__ Sc, const float* __restrict__ cmask,
                       const float* __restrict__ qmask) {
  int blk = blockIdx.x;
  int tid = threadIdx.x;
  if (blk < BB * MM) {
    int b = blk / MM;
    int mcol = blk % MM;
    float vals[7];
    float mx = -1e30f;
    #pragma unroll
    for (int c = 0; c < 7; ++c) {
      int n = tid + c * 64;
      float s = -1e30f;
      if (n < NN)
        s = S[((size_t)b * NN + n) * MM + mcol] - 1e30f * (1.0f - cmask[b * NN + n]);
      vals[c] = s;
      mx = fmaxf(mx, s);
    }
    #pragma unroll
    for (int off = 1; off < 64; off <<= 1) mx = fmaxf(mx, __shfl_xor(mx, off));
    float sum = 0.f;
    #pragma unroll
    for (int c = 0; c < 7; ++c) { vals[c] = __expf(vals[c] - mx); sum += vals[c]; }
    #pragma unroll
    for (int off = 1; off < 64; off <<= 1) sum += __shfl_xor(sum, off);
    float inv = 1.0f / sum;
    #pragma unroll
    for (int c = 0; c < 7; ++c) {
      int n = tid + c * 64;
      if (n < NN) Sc[((size_t)b * NN + n) * MM + mcol] = vals[c] * inv;
    }
  } else {
    int bn = blk - BB * MM;
    int b = bn / NN;
    float s = -1e30f;
    if (tid < MM)
      s = S[(size_t)bn * MM + tid] - 1e30f * (1.0f - qmask[b * MM + tid]);
    float mx = s;
    #pragma unroll
    for (int off = 1; off < 64; off <<= 1) mx = fmaxf(mx, __shfl_xor(mx, off));
    float e = (tid < MM) ? __expf(s - mx) : 0.f;
    float sum = e;
    #pragma unroll
    for (int off = 1; off < 64; off <<= 1) sum += __shfl_xor(sum, off);
    if (tid < MM) Sr[(size_t)bn * MM + tid] = e / sum;
  }
}

// ---------------- U[b,m,d] = sum_k Sc[b,k,m]*C2[b,k,d] ----------------
__global__ void k_U(const float* __restrict__ Sc, const float* __restrict__ C2,
                    float* __restrict__ U) {
  int idx = blockIdx.x * 256 + threadIdx.x;
  if (idx >= BB * MM * 32) return;
  int d4 = idx & 31;
  int rest = idx >> 5;
  int mcol = rest % MM;
  int b = rest / MM;
  const float* psc = Sc + (size_t)b * NN * MM + mcol;
  const float4* pc2 = (const float4*)(C2 + (size_t)b * NN * DD) + d4;
  float4 acc = {0.f, 0.f, 0.f, 0.f};
  #pragma unroll 4
  for (int kk = 0; kk < NN; ++kk) {
    float s = psc[(size_t)kk * MM];
    float4 c = pc2[(size_t)kk * 32];
    acc.x += s * c.x; acc.y += s * c.y; acc.z += s * c.z; acc.w += s * c.w;
  }
  ((float4*)U)[idx] = acc;
}

// ---------------- fused A/Bt + final concat; LDS-staged Q2/Uu/Sr ----------------
// block per (b, 64-n tile): 448 blocks. Writes out = [C2, A, C2*A, C2*Bt] directly.
__global__ __launch_bounds__(256) void k_ABtF(
    const float* __restrict__ Sr, const float* __restrict__ Q2,
    const float* __restrict__ Uu, const float* __restrict__ C2,
    float* __restrict__ out) {
  int blk = blockIdx.x;
  int b = blk / 7, nt = blk % 7;
  int n0 = nt * 64;
  int nv = NN - n0; if (nv > 64) nv = 64;
  __shared__ float Ql[MM * 128];
  __shared__ float Ul[MM * 128];
  __shared__ float Sl[64 * MM];
  int tid = threadIdx.x;
  const float4* q4 = (const float4*)(Q2 + (size_t)b * MM * DD);
  const float4* u4 = (const float4*)(Uu + (size_t)b * MM * DD);
  for (int i = tid; i < MM * 32; i += 256) {
    ((float4*)Ql)[i] = q4[i];
    ((float4*)Ul)[i] = u4[i];
  }
  for (int i = tid; i < 64 * MM; i += 256) {
    int n = i / MM;
    Sl[i] = (n < nv) ? Sr[((size_t)b * NN + n0 + n) * MM + (i - n * MM)] : 0.f;
  }
  __syncthreads();
  int n = tid >> 2;
  if (n >= nv) return;  // no syncs after this point
  int d04 = (tid & 3) * 8;   // float4 index base: 8 float4 = 32 d
  float4 accA[8], accB[8];
  #pragma unroll
  for (int r = 0; r < 8; ++r) {
    accA[r] = {0.f, 0.f, 0.f, 0.f};
    accB[r] = {0.f, 0.f, 0.f, 0.f};
  }
  const float* sp = &Sl[n * MM];
  for (int m = 0; m < MM; ++m) {
    float s = sp[m];
    const float4* qp = (const float4*)&Ql[m * 128] + d04;
    const float4* up = (const float4*)&Ul[m * 128] + d04;
    #pragma unroll
    for (int r = 0; r < 8; ++r) {
      float4 q = qp[r], u = up[r];
      accA[r].x += s * q.x; accA[r].y += s * q.y; accA[r].z += s * q.z; accA[r].w += s * q.w;
      accB[r].x += s * u.x; accB[r].y += s * u.y; accB[r].z += s * u.z; accB[r].w += s * u.w;
    }
  }
  int gn = n0 + n;
  const float4* c4 = (const float4*)(C2 + ((size_t)b * NN + gn) * DD) + d04;
  float4* po = (float4*)(out + (size_t)(b * NN + gn) * 512);
  #pragma unroll
  for (int r = 0; r < 8; ++r) {
    float4 c = c4[r];
    float4 a = accA[r], bt = accB[r];
    po[d04 + r] = c;
    po[32 + d04 + r] = a;
    float4 ca = {c.x * a.x, c.y * a.y, c.z * a.z, c.w * a.w};
    po[64 + d04 + r] = ca;
    float4 cb = {c.x * bt.x, c.y * bt.y, c.z * bt.z, c.w * bt.w};
    po[96 + d04 + r] = cb;
  }
}

extern "C" void kernel_launch(void* const* d_in, const int* in_sizes, int n_in,
                              void* d_out, int out_size, void* d_ws, size_t ws_size,
                              hipStream_t stream) {
  (void)in_sizes; (void)n_in; (void)out_size; (void)ws_size;
  const float* ctx   = (const float*)d_in[0];
  const float* que   = (const float*)d_in[1];
  const float* cmask = (const float*)d_in[2];
  const float* qmask = (const float*)d_in[3];
  const float* ln_g  = (const float*)d_in[4];
  const float* ln_b  = (const float*)d_in[5];
  const float* dw_w  = (const float*)d_in[6];
  const float* dw_b  = (const float*)d_in[7];
  const float* pw_w  = (const float*)d_in[8];
  const float* pw_b  = (const float*)d_in[9];
  const float* Wq    = (const float*)d_in[10];
  const float* bq    = (const float*)d_in[11];
  const float* Wk    = (const float*)d_in[12];
  const float* bk    = (const float*)d_in[13];
  const float* Wv    = (const float*)d_in[14];
  const float* bv    = (const float*)d_in[15];
  const float* Wo    = (const float*)d_in[16];
  const float* bo    = (const float*)d_in[17];
  const float* Wfc   = (const float*)d_in[18];
  const float* bfc   = (const float*)d_in[19];
  const float* cq_wc = (const float*)d_in[20];
  const float* cq_wq = (const float*)d_in[21];
  const float* cq_wm = (const float*)d_in[22];
  const float* cq_b  = (const float*)d_in[23];
  float* out = (float*)d_out;
  float* ws = (float*)d_ws;

  float* Cb   = ws;
  float* Qb   = Cb + SZ_C;
  float* t1C  = Qb + SZ_Q;
  float* t1Q  = t1C + SZ_C;
  float* t2C  = t1Q + SZ_Q;
  float* t2Q  = t2C + SZ_C;
  float* t3C  = t2Q + SZ_Q;
  float* t3Q  = t3C + SZ_C;
  float* t4C  = t3Q + SZ_Q;
  float* t4Q  = t4C + SZ_C;
  float* mu0  = t4Q + SZ_Q;
  float* inv0 = mu0 + SSTAT;
  float* mu1  = inv0 + SSTAT;
  float* inv1 = mu1 + SSTAT;
  float* Wcan = inv1 + SSTAT;

  k_transposeW<<<(9 * 16384 + 255) / 256, 256, 0, stream>>>(pw_w, Wo, Wfc, Wq, Wk, Wv, Wcan);
  k_pestats<<<512, 256, 0, stream>>>(ctx, que, Cb, Qb, mu0, inv0);

  // conv layers: fused LN+dwconv+pwGEMM+relu+residual+stats. Ping-pong Cb <-> t1.
  for (int i = 0; i < NC; ++i) {
    const float* inC = (i & 1) ? t1C : Cb;
    const float* inQ = (i & 1) ? t1Q : Qb;
    float* oC = (i & 1) ? Cb : t1C;
    float* oQ = (i & 1) ? Qb : t1Q;
    const float* mI = (i & 1) ? mu1 : mu0;
    const float* iI = (i & 1) ? inv1 : inv0;
    float* mO = (i & 1) ? mu0 : mu1;
    float* iO = (i & 1) ? inv0 : inv1;
    k_convgemm<<<512, 256, 0, stream>>>(inC, inQ, oC, oQ,
                                        Wcan + (size_t)i * 16384, pw_b + (size_t)i * DD,
                                        dw_w + (size_t)i * DD * KW, dw_b + (size_t)i * DD,
                                        mI, iI, mO, iO, ln_g, ln_b);
  }
  // after 4 layers, result in Cb with stats in mu0/inv0.
  k_gemm_qkv<<<1536, 256, 0, stream>>>(Cb, Qb, t1C, t1Q, t2C, t2Q, t3C, t3Q,
                                       Wcan, bq, bk, bv, mu0, inv0, ln_g, ln_b);
  k_attn2<<<1536, 256, 0, stream>>>(t1C, t2C, t3C, t1Q, t2Q, t3Q, cmask, qmask, t4C, t4Q);
  // Wo projection: +residual into Cb, stats -> mu1/inv1
  k_gemm64<0, 1, 1><<<512, 256, 0, stream>>>(t4C, t4Q, Cb, Qb, Wcan + 4 * 16384, bo,
                                             mu0, inv0, mu1, inv1, ln_g, ln_b);
  // FFN: LN(mu1) + GEMM + residual, in-place on Cb
  k_gemm64<1, 1, 0><<<512, 256, 0, stream>>>(Cb, Qb, Cb, Qb, Wcan + 5 * 16384, bfc,
                                             mu1, inv1, mu0, inv0, ln_g, ln_b);

  // ---- context-query attention ----
  float* C2  = t1C;
  float* Q2  = t1Q;
  float* S   = t2C;
  float* Sr  = t2C + 1638400;
  float* Scb = t3C;
  float* Uu  = t2Q;
  float* cd  = t3Q;
  float* qd  = t4Q;

  k_prep<<<3953, 256, 0, stream>>>(Cb, Qb, C2, Q2, cq_wc, cq_wq, cd, qd);
  k_S<<<(BB * NN * MM + 255) / 256, 256, 0, stream>>>(C2, Q2, cd, qd, cq_wm, cq_b, S);
  k_smax<<<BB * MM + BB * NN, 64, 0, stream>>>(S, Sr, Scb, cmask, qmask);
  k_U<<<(BB * MM * 32 + 255) / 256, 256, 0, stream>>>(Scb, C2, Uu);
  k_ABtF<<<448, 256, 0, stream>>>(Sr, Q2, Uu, C2, out);
}

// Round 5
// 721.450 us; speedup vs baseline: 14.9394x; 14.9394x over previous
//
#include <hip/hip_runtime.h>
#include <math.h>

#define BB 64
#define DD 128
#define NN 400
#define MM 50
#define HH 8
#define KDIM 16
#define NC 4
#define KW 7

#define SZ_C (BB * DD * NN)   // 3,276,800
#define SZ_Q (BB * DD * MM)   //   409,600
#define SSTAT (BB * NN + BB * MM)  // 28,800; q stats at offset BB*NN

// ---------------- canonical weight transpose: Wcan[m][d][e] ----------------
__global__ void k_transposeW(const float* __restrict__ pw_w, const float* __restrict__ Wo,
                             const float* __restrict__ Wfc, const float* __restrict__ Wq,
                             const float* __restrict__ Wk, const float* __restrict__ Wv,
                             float* __restrict__ Wcan) {
  int idx = blockIdx.x * 256 + threadIdx.x;
  if (idx >= 9 * 16384) return;
  int m = idx >> 14;
  int r = idx & 16383;
  int d = r >> 7, e = r & 127;
  float v;
  if (m < 4) v = pw_w[m * 16384 + e * 128 + d];
  else if (m == 4) v = Wo[d * 128 + e];
  else if (m == 5) v = Wfc[e * 128 + d];
  else {
    const float* W = (m == 6) ? Wq : (m == 7) ? Wk : Wv;
    v = W[((e >> 4) * 128 + d) * 16 + (e & 15)];
  }
  Wcan[idx] = v;
}

// ---------------- fused PE add + LN stats ----------------
__global__ void k_pestats(const float* __restrict__ xC, const float* __restrict__ xQ,
                          float* __restrict__ yC, float* __restrict__ yQ,
                          float* __restrict__ mu, float* __restrict__ inv) {
  int blk = blockIdx.x;
  const float* x; float* y; int L, l0, b, soff;
  if (blk < 448) { b = blk / 7; l0 = (blk % 7) * 64; x = xC; y = yC; L = NN; soff = 0; }
  else { b = blk - 448; l0 = 0; x = xQ; y = yQ; L = MM; soff = BB * NN; }
  int tid = threadIdx.x;
  int ll = tid & 63;
  int dq = tid >> 6;
  int l = l0 + ll;
  __shared__ float s_sum[4][64], s_sq[4][64];
  float sum = 0.f, sq = 0.f;
  if (l < L) {
    const float* px = x + (size_t)b * DD * L + l;
    float* py = y + (size_t)b * DD * L + l;
    for (int d = dq * 32; d < dq * 32 + 32; ++d) {
      int de = d & ~1;
      float freq = __expf((float)de * (-9.210340371976184f / 128.0f));
      float ph = (d & 1) ? 1.5707963267948966f : 0.0f;
      float v = px[(size_t)d * L] + sinf((float)l * freq + ph);
      py[(size_t)d * L] = v;
      sum += v; sq += v * v;
    }
  }
  s_sum[dq][ll] = sum; s_sq[dq][ll] = sq;
  __syncthreads();
  if (dq == 0 && l < L) {
    float ts = s_sum[0][ll] + s_sum[1][ll] + s_sum[2][ll] + s_sum[3][ll];
    float tq = s_sq[0][ll] + s_sq[1][ll] + s_sq[2][ll] + s_sq[3][ll];
    float m = ts * (1.0f / 128.0f);
    float var = (tq - 128.0f * m * m) * (1.0f / 127.0f);
    float sd = sqrtf(fmaxf(var, 0.f));
    mu[soff + b * L + l] = m;
    inv[soff + b * L + l] = 1.0f / (sd + 1e-6f);
  }
}

// ---------------- fused conv layer, 64-col tiles (512 blocks = 2/CU) ----------------
// R3-proven staging footprint: per round, each thread produces 4 conv outputs
// (window xw[10], loads xr[12]); 2 rounds cover 32 rows x 64 cols.
// __launch_bounds__(256,2) pins VGPR <= 128 (R4's 8-output variant spilled acc
// to scratch: 256 VGPR, 3.7 GB scratch FETCH, 28x slowdown).
__global__ __launch_bounds__(256, 2) void k_convgemm(
    const float* __restrict__ xC, const float* __restrict__ xQ,
    float* __restrict__ outC, float* __restrict__ outQ,
    const float* __restrict__ Wc, const float* __restrict__ pwb,
    const float* __restrict__ dww, const float* __restrict__ dwb,
    const float* __restrict__ muI, const float* __restrict__ invI,
    float* __restrict__ muO, float* __restrict__ invO,
    const float* __restrict__ g, const float* __restrict__ beta) {
  int blk = blockIdx.x;
  int b = blk >> 3, tile = blk & 7;
  const float* x; float* out; int L, l0, soff;
  if (tile < 7) { x = xC; out = outC; L = NN; l0 = tile * 64; soff = 0; }
  else { x = xQ; out = outQ; L = MM; l0 = 0; soff = BB * NN; }
  __shared__ float Wl[32 * 128];
  __shared__ float Xl[32 * 64];
  __shared__ float Sm[70], Si[70];   // stats halo [l0-3, l0+67)
  int tid = threadIdx.x;
  const float* xb = x + (size_t)b * DD * L;
  for (int t = tid; t < 70; t += 256) {
    int gl = l0 + t - 3;
    bool ok = (gl >= 0 && gl < L);
    Sm[t] = ok ? muI[soff + b * L + gl] : 0.f;
    Si[t] = ok ? invI[soff + b * L + gl] : 0.f;
  }
  float acc[8][4];
  #pragma unroll
  for (int i = 0; i < 8; ++i)
    #pragma unroll
    for (int j = 0; j < 4; ++j) acc[i][j] = 0.f;
  __syncthreads();
  for (int kc = 0; kc < 4; ++kc) {
    int d0 = kc * 32;
    // W staging (float4)
    #pragma unroll
    for (int i = 0; i < 4; ++i) {
      int idx = i * 256 + tid;
      ((float4*)Wl)[idx] = ((const float4*)Wc)[(size_t)d0 * 32 + idx];
    }
    // X staging: LN + depthwise conv; 2 rounds x (1 row, 4 cols) per thread
    #pragma unroll
    for (int r = 0; r < 2; ++r) {
      int k = r * 16 + (tid >> 4);
      int d = d0 + k;
      int c0 = (tid & 15) * 4;
      const float* xrow = xb + (size_t)d * L;
      float gd = g[d], bd = beta[d];
      float wv[7];
      #pragma unroll
      for (int u = 0; u < 7; ++u) wv[u] = dww[d * 7 + u];
      float dbv = dwb[d];
      float xw[10];
      int gbase = l0 + c0 - 3;  // xw[s] = LN'd x at gbase+s, s in [0,10)
      if (gbase >= 1 && gbase + 11 <= L && (((unsigned)(d * L + gbase - 1)) & 3u) == 0u) {
        const float4* p = (const float4*)&xrow[gbase - 1];
        float4 A = p[0], Bv = p[1], Cv = p[2];
        float xr[12] = {A.x, A.y, A.z, A.w, Bv.x, Bv.y, Bv.z, Bv.w, Cv.x, Cv.y, Cv.z, Cv.w};
        #pragma unroll
        for (int s = 0; s < 10; ++s)
          xw[s] = gd * (xr[s + 1] - Sm[c0 + s]) * Si[c0 + s] + bd;
      } else {
        #pragma unroll
        for (int s = 0; s < 10; ++s) {
          int gl = gbase + s;
          float v = 0.f;  // zero-pad AFTER LN
          if (gl >= 0 && gl < L)
            v = gd * (xrow[gl] - Sm[c0 + s]) * Si[c0 + s] + bd;
          xw[s] = v;
        }
      }
      float4 o;
      o.x = dbv; o.y = dbv; o.z = dbv; o.w = dbv;
      #pragma unroll
      for (int u = 0; u < 7; ++u) {
        o.x += wv[u] * xw[u];
        o.y += wv[u] * xw[u + 1];
        o.z += wv[u] * xw[u + 2];
        o.w += wv[u] * xw[u + 3];
      }
      *(float4*)&Xl[k * 64 + c0] = o;
    }
    __syncthreads();
    int e0 = (tid >> 4) * 8, cq = (tid & 15) * 4;
    for (int k = 0; k < 32; ++k) {
      const float4* wp = (const float4*)&Wl[k * 128 + e0];
      float4 w0 = wp[0], w1 = wp[1];
      float4 xv = *(const float4*)&Xl[k * 64 + cq];
      float we[8] = {w0.x, w0.y, w0.z, w0.w, w1.x, w1.y, w1.z, w1.w};
      float xe[4] = {xv.x, xv.y, xv.z, xv.w};
      #pragma unroll
      for (int i = 0; i < 8; ++i)
        #pragma unroll
        for (int j = 0; j < 4; ++j) acc[i][j] += we[i] * xe[j];
    }
    __syncthreads();
  }
  // epilogue: relu + residual + per-column stats
  int e0 = (tid >> 4) * 8, cq = (tid & 15) * 4;
  float ssum[4], ssq[4];
  #pragma unroll
  for (int j = 0; j < 4; ++j) { ssum[j] = 0.f; ssq[j] = 0.f; }
  #pragma unroll
  for (int i = 0; i < 8; ++i) {
    float bi = pwb[e0 + i];
    float* po = out + ((size_t)b * DD + e0 + i) * L;
    const float* pr = xb + (size_t)(e0 + i) * L;
    #pragma unroll
    for (int j = 0; j < 4; ++j) {
      int l = l0 + cq + j;
      if (l < L) {
        float v = fmaxf(acc[i][j] + bi, 0.f) + pr[l];
        po[l] = v;
        ssum[j] += v; ssq[j] += v * v;
      }
    }
  }
  int grp = tid >> 4;
  #pragma unroll
  for (int j = 0; j < 4; ++j) {
    Xl[grp * 64 + cq + j] = ssum[j];
    Wl[grp * 64 + cq + j] = ssq[j];
  }
  __syncthreads();
  if (tid < 64) {
    int l = l0 + tid;
    if (l < L) {
      float ts = 0.f, tq = 0.f;
      #pragma unroll
      for (int gg = 0; gg < 16; ++gg) { ts += Xl[gg * 64 + tid]; tq += Wl[gg * 64 + tid]; }
      float m = ts * (1.0f / 128.0f);
      float var = (tq - 128.0f * m * m) * (1.0f / 127.0f);
      float sd = sqrtf(fmaxf(var, 0.f));
      muO[soff + b * L + l] = m;
      invO[soff + b * L + l] = 1.0f / (sd + 1e-6f);
    }
  }
}

// ---------------- 128x64 GEMM tiles, 512 blocks ----------------
template <int LNF, int ACT, int STATS>
__global__ __launch_bounds__(256) void k_gemm64(
    const float* __restrict__ xC, const float* __restrict__ xQ,
    float* __restrict__ outC, float* __restrict__ outQ,
    const float* __restrict__ Wc, const float* __restrict__ bias,
    const float* __restrict__ mu, const float* __restrict__ inv,
    float* __restrict__ muO, float* __restrict__ invO,
    const float* __restrict__ g, const float* __restrict__ beta) {
  int blk = blockIdx.x;
  int b = blk >> 3, tile = blk & 7;
  const float* x; float* out; int L, l0, soff;
  if (tile < 7) { x = xC; out = outC; L = NN; l0 = tile * 64; soff = 0; }
  else { x = xQ; out = outQ; L = MM; l0 = 0; soff = BB * NN; }
  __shared__ float Wl[32 * 128];
  __shared__ float Xl[32 * 64];
  int tid = threadIdx.x;
  float acc[8][4];
  #pragma unroll
  for (int i = 0; i < 8; ++i)
    #pragma unroll
    for (int j = 0; j < 4; ++j) acc[i][j] = 0.f;
  const float* xb = x + (size_t)b * DD * L;
  const float* pmu = mu + soff + b * L;
  const float* pin = inv + soff + b * L;
  for (int kc = 0; kc < 4; ++kc) {
    int d0 = kc * 32;
    #pragma unroll
    for (int i = 0; i < 4; ++i) {
      int idx = i * 256 + tid;
      ((float4*)Wl)[idx] = ((const float4*)Wc)[(size_t)d0 * 32 + idx];
    }
    #pragma unroll
    for (int t = 0; t < 8; ++t) {
      int idx = t * 256 + tid;
      int k = idx >> 6, l = idx & 63;
      float v = 0.f;
      int gl = l0 + l;
      if (gl < L) {
        v = xb[(size_t)(d0 + k) * L + gl];
        if (LNF) v = g[d0 + k] * (v - pmu[gl]) * pin[gl] + beta[d0 + k];
      }
      Xl[idx] = v;
    }
    __syncthreads();
    int e0 = (tid >> 4) * 8, cq = (tid & 15) * 4;
    for (int k = 0; k < 32; ++k) {
      const float4* wp = (const float4*)&Wl[k * 128 + e0];
      float4 w0 = wp[0], w1 = wp[1];
      float4 xv = *(const float4*)&Xl[k * 64 + cq];
      float we[8] = {w0.x, w0.y, w0.z, w0.w, w1.x, w1.y, w1.z, w1.w};
      float xe[4] = {xv.x, xv.y, xv.z, xv.w};
      #pragma unroll
      for (int i = 0; i < 8; ++i)
        #pragma unroll
        for (int j = 0; j < 4; ++j) acc[i][j] += we[i] * xe[j];
    }
    __syncthreads();
  }
  int e0 = (tid >> 4) * 8, cq = (tid & 15) * 4;
  float ssum[4], ssq[4];
  #pragma unroll
  for (int j = 0; j < 4; ++j) { ssum[j] = 0.f; ssq[j] = 0.f; }
  #pragma unroll
  for (int i = 0; i < 8; ++i) {
    float bi = bias[e0 + i];
    float* po = out + ((size_t)b * DD + e0 + i) * L;
    #pragma unroll
    for (int j = 0; j < 4; ++j) {
      int l = l0 + cq + j;
      if (l < L) {
        float v = acc[i][j] + bi;
        if (ACT != 0) v += po[l];
        po[l] = v;
        if (STATS) { ssum[j] += v; ssq[j] += v * v; }
      }
    }
  }
  if (STATS) {
    int grp = tid >> 4;
    #pragma unroll
    for (int j = 0; j < 4; ++j) {
      Xl[grp * 64 + cq + j] = ssum[j];
      Wl[grp * 64 + cq + j] = ssq[j];
    }
    __syncthreads();
    if (tid < 64) {
      int l = l0 + tid;
      if (l < L) {
        float ts = 0.f, tq = 0.f;
        #pragma unroll
        for (int gg = 0; gg < 16; ++gg) { ts += Xl[gg * 64 + tid]; tq += Wl[gg * 64 + tid]; }
        float m = ts * (1.0f / 128.0f);
        float var = (tq - 128.0f * m * m) * (1.0f / 127.0f);
        float sd = sqrtf(fmaxf(var, 0.f));
        muO[soff + b * L + l] = m;
        invO[soff + b * L + l] = 1.0f / (sd + 1e-6f);
      }
    }
  }
}

// ---------------- fused QKV GEMM: 3 x 512 blocks ----------------
__global__ __launch_bounds__(256) void k_gemm_qkv(
    const float* __restrict__ xC, const float* __restrict__ xQ,
    float* __restrict__ o1C, float* __restrict__ o1Q,
    float* __restrict__ o2C, float* __restrict__ o2Q,
    float* __restrict__ o3C, float* __restrict__ o3Q,
    const float* __restrict__ Wcan,
    const float* __restrict__ bq, const float* __restrict__ bk, const float* __restrict__ bv,
    const float* __restrict__ mu, const float* __restrict__ inv,
    const float* __restrict__ g, const float* __restrict__ beta) {
  int blk0 = blockIdx.x;
  int grp = blk0 >> 9;
  int blk = blk0 & 511;
  const float* Wc = Wcan + (size_t)(6 + grp) * 16384;
  const float* bias = (grp == 0) ? bq : (grp == 1) ? bk : bv;
  float* oC = (grp == 0) ? o1C : (grp == 1) ? o2C : o3C;
  float* oQ = (grp == 0) ? o1Q : (grp == 1) ? o2Q : o3Q;
  int b = blk >> 3, tile = blk & 7;
  const float* x; float* out; int L, l0, soff;
  if (tile < 7) { x = xC; out = oC; L = NN; l0 = tile * 64; soff = 0; }
  else { x = xQ; out = oQ; L = MM; l0 = 0; soff = BB * NN; }
  __shared__ float Wl[32 * 128];
  __shared__ float Xl[32 * 64];
  int tid = threadIdx.x;
  float acc[8][4];
  #pragma unroll
  for (int i = 0; i < 8; ++i)
    #pragma unroll
    for (int j = 0; j < 4; ++j) acc[i][j] = 0.f;
  const float* xb = x + (size_t)b * DD * L;
  const float* pmu = mu + soff + b * L;
  const float* pin = inv + soff + b * L;
  for (int kc = 0; kc < 4; ++kc) {
    int d0 = kc * 32;
    #pragma unroll
    for (int i = 0; i < 4; ++i) {
      int idx = i * 256 + tid;
      ((float4*)Wl)[idx] = ((const float4*)Wc)[(size_t)d0 * 32 + idx];
    }
    #pragma unroll
    for (int t = 0; t < 8; ++t) {
      int idx = t * 256 + tid;
      int k = idx >> 6, l = idx & 63;
      float v = 0.f;
      int gl = l0 + l;
      if (gl < L) {
        v = xb[(size_t)(d0 + k) * L + gl];
        v = g[d0 + k] * (v - pmu[gl]) * pin[gl] + beta[d0 + k];
      }
      Xl[idx] = v;
    }
    __syncthreads();
    int e0 = (tid >> 4) * 8, cq = (tid & 15) * 4;
    for (int k = 0; k < 32; ++k) {
      const float4* wp = (const float4*)&Wl[k * 128 + e0];
      float4 w0 = wp[0], w1 = wp[1];
      float4 xv = *(const float4*)&Xl[k * 64 + cq];
      float we[8] = {w0.x, w0.y, w0.z, w0.w, w1.x, w1.y, w1.z, w1.w};
      float xe[4] = {xv.x, xv.y, xv.z, xv.w};
      #pragma unroll
      for (int i = 0; i < 8; ++i)
        #pragma unroll
        for (int j = 0; j < 4; ++j) acc[i][j] += we[i] * xe[j];
    }
    __syncthreads();
  }
  int e0 = (tid >> 4) * 8, cq = (tid & 15) * 4;
  #pragma unroll
  for (int i = 0; i < 8; ++i) {
    float bi = bias[e0 + i];
    float* po = out + ((size_t)b * DD + e0 + i) * L;
    #pragma unroll
    for (int j = 0; j < 4; ++j) {
      int l = l0 + cq + j;
      if (l < L) po[l] = acc[i][j] + bi;
    }
  }
}

// ---------------- attention (unchanged) ----------------
__global__ __launch_bounds__(256) void k_attn2(
    const float* __restrict__ qC, const float* __restrict__ kC, const float* __restrict__ vC,
    const float* __restrict__ qQ, const float* __restrict__ kQ, const float* __restrict__ vQ,
    const float* __restrict__ cmask, const float* __restrict__ qmask,
    float* __restrict__ oC, float* __restrict__ oQ) {
  int blk = blockIdx.x;
  const float *qp, *kp, *vp, *mk; float* op; int L, b, h, q0, qcnt;
  if (blk < 1024) {
    b = blk >> 4; h = (blk >> 1) & 7; int half = blk & 1;
    qp = qC; kp = kC; vp = vC; mk = cmask; op = oC; L = NN;
    q0 = half * 256; qcnt = half ? (NN - 256) : 256;
  } else {
    int bb = blk - 1024; b = bb >> 3; h = bb & 7;
    qp = qQ; kp = kQ; vp = vQ; mk = qmask; op = oQ; L = MM;
    q0 = 0; qcnt = MM;
  }
  __shared__ float Kl[NN * KDIM];
  __shared__ float Vl[NN * KDIM];
  __shared__ float Ml[NN];
  int tid = threadIdx.x;
  size_t base = ((size_t)b * DD + h * KDIM) * L;
  int KP = (L + 7) & ~7;
  for (int idx = tid; idx < KDIM * L; idx += 256) {
    int t = idx / L, j = idx - t * L;
    Kl[j * KDIM + t] = kp[base + (size_t)t * L + j];
    Vl[j * KDIM + t] = vp[base + (size_t)t * L + j];
  }
  for (int idx = tid; idx < (KP - L) * KDIM; idx += 256) {
    int j = L + (idx >> 4), t = idx & 15;
    Kl[j * KDIM + t] = 0.f; Vl[j * KDIM + t] = 0.f;
  }
  for (int j = tid; j < KP; j += 256)
    Ml[j] = (j < L) ? -1e30f * (1.0f - mk[b * L + j]) : -1e30f;
  __syncthreads();
  if (tid >= qcnt) return;

  int i = q0 + tid;
  float q[KDIM];
  #pragma unroll
  for (int t = 0; t < KDIM; ++t) q[t] = qp[base + (size_t)t * L + i] * 0.25f;
  float m = -1e30f, ls = 0.f;
  float acc[KDIM];
  #pragma unroll
  for (int t = 0; t < KDIM; ++t) acc[t] = 0.f;
  for (int j0 = 0; j0 < KP; j0 += 8) {
    const float4* mp = (const float4*)&Ml[j0];
    float4 ma0 = mp[0], ma1 = mp[1];
    float mav[8] = {ma0.x, ma0.y, ma0.z, ma0.w, ma1.x, ma1.y, ma1.z, ma1.w};
    float s[8];
    #pragma unroll
    for (int jj = 0; jj < 8; ++jj) {
      const float4* kf = (const float4*)&Kl[(j0 + jj) * KDIM];
      float4 k0 = kf[0], k1 = kf[1], k2 = kf[2], k3 = kf[3];
      float da = q[0] * k0.x + q[1] * k0.y + q[2] * k0.z + q[3] * k0.w
               + q[4] * k1.x + q[5] * k1.y + q[6] * k1.z + q[7] * k1.w;
      float db = q[8] * k2.x + q[9] * k2.y + q[10] * k2.z + q[11] * k2.w
               + q[12] * k3.x + q[13] * k3.y + q[14] * k3.z + q[15] * k3.w;
      s[jj] = da + db + mav[jj];
    }
    float cm = s[0];
    #pragma unroll
    for (int jj = 1; jj < 8; ++jj) cm = fmaxf(cm, s[jj]);
    if (cm > m) {
      float sc = __expf(m - cm);
      ls *= sc;
      #pragma unroll
      for (int t = 0; t < KDIM; ++t) acc[t] *= sc;
      m = cm;
    }
    #pragma unroll
    for (int jj = 0; jj < 8; ++jj) {
      float p = __expf(s[jj] - m);
      ls += p;
      const float4* vf = (const float4*)&Vl[(j0 + jj) * KDIM];
      float4 v0 = vf[0], v1 = vf[1], v2 = vf[2], v3 = vf[3];
      acc[0] += p * v0.x;  acc[1] += p * v0.y;  acc[2] += p * v0.z;  acc[3] += p * v0.w;
      acc[4] += p * v1.x;  acc[5] += p * v1.y;  acc[6] += p * v1.z;  acc[7] += p * v1.w;
      acc[8] += p * v2.x;  acc[9] += p * v2.y;  acc[10] += p * v2.z; acc[11] += p * v2.w;
      acc[12] += p * v3.x; acc[13] += p * v3.y; acc[14] += p * v3.z; acc[15] += p * v3.w;
    }
  }
  float invl = 1.0f / ls;
  #pragma unroll
  for (int t = 0; t < KDIM; ++t)
    op[base + (size_t)t * L + i] = acc[t] * invl;
}

// ---------------- fused prep: tiled transposes + dotD ----------------
__global__ void k_prep(const float* __restrict__ Cb, const float* __restrict__ Qb,
                       float* __restrict__ C2, float* __restrict__ Q2,
                       const float* __restrict__ wc, const float* __restrict__ wq,
                       float* __restrict__ cd, float* __restrict__ qd) {
  int blk = blockIdx.x, tid = threadIdx.x;
  if (blk < 3840) {
    const float* X; float* Y; int L, rem;
    if (blk < 3328) { X = Cb; Y = C2; L = NN; rem = blk; }
    else { X = Qb; Y = Q2; L = MM; rem = blk - 3328; }
    int ntl = (L + 31) / 32;
    int b = rem / (4 * ntl);
    int r2 = rem % (4 * ntl);
    int d0 = (r2 / ntl) * 32;
    int l0 = (r2 % ntl) * 32;
    __shared__ float T[32][33];
    int c = tid & 31, r8 = tid >> 5;
    const float* xb = X + (size_t)b * DD * L;
    #pragma unroll
    for (int k = 0; k < 4; ++k) {
      int r = r8 + k * 8;
      int l = l0 + c;
      T[r][c] = (l < L) ? xb[(size_t)(d0 + r) * L + l] : 0.f;
    }
    __syncthreads();
    float* yb = Y + (size_t)b * L * DD;
    #pragma unroll
    for (int k = 0; k < 4; ++k) {
      int rr = r8 + k * 8;
      int l = l0 + rr;
      if (l < L) yb[(size_t)l * DD + d0 + c] = T[c][rr];
    }
  } else if (blk < 3940) {
    int idx = (blk - 3840) * 256 + tid;
    if (idx < BB * NN) {
      int l = idx % NN, b = idx / NN;
      const float* px = Cb + (size_t)b * DD * NN + l;
      float acc = 0.f;
      for (int d = 0; d < DD; ++d) acc += px[(size_t)d * NN] * wc[d];
      cd[idx] = acc;
    }
  } else {
    int idx = (blk - 3940) * 256 + tid;
    if (idx < BB * MM) {
      int l = idx % MM, b = idx / MM;
      const float* px = Qb + (size_t)b * DD * MM + l;
      float acc = 0.f;
      for (int d = 0; d < DD; ++d) acc += px[(size_t)d * MM] * wq[d];
      qd[idx] = acc;
    }
  }
}

// ---------------- S[b,n,m] trilinear ----------------
__global__ void k_S(const float* __restrict__ C2, const float* __restrict__ Q2,
                    const float* __restrict__ cd, const float* __restrict__ qd,
                    const float* __restrict__ wm, const float* __restrict__ bias,
                    float* __restrict__ S) {
  int idx = blockIdx.x * 256 + threadIdx.x;
  if (idx >= BB * NN * MM) return;
  int mcol = idx % MM;
  int n = (idx / MM) % NN;
  int b = idx / (MM * NN);
  const float4* pc = (const float4*)(C2 + ((size_t)b * NN + n) * DD);
  const float4* pq = (const float4*)(Q2 + ((size_t)b * MM + mcol) * DD);
  const float4* pw = (const float4*)wm;
  float a0 = 0.f, a1 = 0.f;
  #pragma unroll 4
  for (int d4 = 0; d4 < 32; d4 += 2) {
    float4 c0 = pc[d4], w0 = pw[d4], q0 = pq[d4];
    float4 c1 = pc[d4 + 1], w1 = pw[d4 + 1], q1 = pq[d4 + 1];
    a0 += (c0.x * w0.x) * q0.x + (c0.y * w0.y) * q0.y + (c0.z * w0.z) * q0.z + (c0.w * w0.w) * q0.w;
    a1 += (c1.x * w1.x) * q1.x + (c1.y * w1.y) * q1.y + (c1.z * w1.z) * q1.z + (c1.w * w1.w) * q1.w;
  }
  S[idx] = a0 + a1 + cd[b * NN + n] + qd[b * MM + mcol] + bias[0];
}

// ---------------- merged softmaxes ----------------
__global__ void k_smax(const float* __restrict__ S, float* __restrict__ Sr,
                       float* __restrict__ Sc, const float* __restrict__ cmask,
                       const float* __restrict__ qmask) {
  int blk = blockIdx.x;
  int tid = threadIdx.x;
  if (blk < BB * MM) {
    int b = blk / MM;
    int mcol = blk % MM;
    float vals[7];
    float mx = -1e30f;
    #pragma unroll
    for (int c = 0; c < 7; ++c) {
      int n = tid + c * 64;
      float s = -1e30f;
      if (n < NN)
        s = S[((size_t)b * NN + n) * MM + mcol] - 1e30f * (1.0f - cmask[b * NN + n]);
      vals[c] = s;
      mx = fmaxf(mx, s);
    }
    #pragma unroll
    for (int off = 1; off < 64; off <<= 1) mx = fmaxf(mx, __shfl_xor(mx, off));
    float sum = 0.f;
    #pragma unroll
    for (int c = 0; c < 7; ++c) { vals[c] = __expf(vals[c] - mx); sum += vals[c]; }
    #pragma unroll
    for (int off = 1; off < 64; off <<= 1) sum += __shfl_xor(sum, off);
    float inv = 1.0f / sum;
    #pragma unroll
    for (int c = 0; c < 7; ++c) {
      int n = tid + c * 64;
      if (n < NN) Sc[((size_t)b * NN + n) * MM + mcol] = vals[c] * inv;
    }
  } else {
    int bn = blk - BB * MM;
    int b = bn / NN;
    float s = -1e30f;
    if (tid < MM)
      s = S[(size_t)bn * MM + tid] - 1e30f * (1.0f - qmask[b * MM + tid]);
    float mx = s;
    #pragma unroll
    for (int off = 1; off < 64; off <<= 1) mx = fmaxf(mx, __shfl_xor(mx, off));
    float e = (tid < MM) ? __expf(s - mx) : 0.f;
    float sum = e;
    #pragma unroll
    for (int off = 1; off < 64; off <<= 1) sum += __shfl_xor(sum, off);
    if (tid < MM) Sr[(size_t)bn * MM + tid] = e / sum;
  }
}

// ---------------- U[b,m,d] = sum_k Sc[b,k,m]*C2[b,k,d] ----------------
__global__ void k_U(const float* __restrict__ Sc, const float* __restrict__ C2,
                    float* __restrict__ U) {
  int idx = blockIdx.x * 256 + threadIdx.x;
  if (idx >= BB * MM * 32) return;
  int d4 = idx & 31;
  int rest = idx >> 5;
  int mcol = rest % MM;
  int b = rest / MM;
  const float* psc = Sc + (size_t)b * NN * MM + mcol;
  const float4* pc2 = (const float4*)(C2 + (size_t)b * NN * DD) + d4;
  float4 acc = {0.f, 0.f, 0.f, 0.f};
  #pragma unroll 4
  for (int kk = 0; kk < NN; ++kk) {
    float s = psc[(size_t)kk * MM];
    float4 c = pc2[(size_t)kk * 32];
    acc.x += s * c.x; acc.y += s * c.y; acc.z += s * c.z; acc.w += s * c.w;
  }
  ((float4*)U)[idx] = acc;
}

// ---------------- fused A/Bt + final concat; LDS-staged Q2/Uu/Sr ----------------
__global__ __launch_bounds__(256) void k_ABtF(
    const float* __restrict__ Sr, const float* __restrict__ Q2,
    const float* __restrict__ Uu, const float* __restrict__ C2,
    float* __restrict__ out) {
  int blk = blockIdx.x;
  int b = blk / 7, nt = blk % 7;
  int n0 = nt * 64;
  int nv = NN - n0; if (nv > 64) nv = 64;
  __shared__ float Ql[MM * 128];
  __shared__ float Ul[MM * 128];
  __shared__ float Sl[64 * MM];
  int tid = threadIdx.x;
  const float4* q4 = (const float4*)(Q2 + (size_t)b * MM * DD);
  const float4* u4 = (const float4*)(Uu + (size_t)b * MM * DD);
  for (int i = tid; i < MM * 32; i += 256) {
    ((float4*)Ql)[i] = q4[i];
    ((float4*)Ul)[i] = u4[i];
  }
  for (int i = tid; i < 64 * MM; i += 256) {
    int n = i / MM;
    Sl[i] = (n < nv) ? Sr[((size_t)b * NN + n0 + n) * MM + (i - n * MM)] : 0.f;
  }
  __syncthreads();
  int n = tid >> 2;
  if (n >= nv) return;
  int d04 = (tid & 3) * 8;
  float4 accA[8], accB[8];
  #pragma unroll
  for (int r = 0; r < 8; ++r) {
    accA[r] = {0.f, 0.f, 0.f, 0.f};
    accB[r] = {0.f, 0.f, 0.f, 0.f};
  }
  const float* sp = &Sl[n * MM];
  for (int m = 0; m < MM; ++m) {
    float s = sp[m];
    const float4* qp = (const float4*)&Ql[m * 128] + d04;
    const float4* up = (const float4*)&Ul[m * 128] + d04;
    #pragma unroll
    for (int r = 0; r < 8; ++r) {
      float4 q = qp[r], u = up[r];
      accA[r].x += s * q.x; accA[r].y += s * q.y; accA[r].z += s * q.z; accA[r].w += s * q.w;
      accB[r].x += s * u.x; accB[r].y += s * u.y; accB[r].z += s * u.z; accB[r].w += s * u.w;
    }
  }
  int gn = n0 + n;
  const float4* c4 = (const float4*)(C2 + ((size_t)b * NN + gn) * DD) + d04;
  float4* po = (float4*)(out + (size_t)(b * NN + gn) * 512);
  #pragma unroll
  for (int r = 0; r < 8; ++r) {
    float4 c = c4[r];
    float4 a = accA[r], bt = accB[r];
    po[d04 + r] = c;
    po[32 + d04 + r] = a;
    float4 ca = {c.x * a.x, c.y * a.y, c.z * a.z, c.w * a.w};
    po[64 + d04 + r] = ca;
    float4 cb = {c.x * bt.x, c.y * bt.y, c.z * bt.z, c.w * bt.w};
    po[96 + d04 + r] = cb;
  }
}

extern "C" void kernel_launch(void* const* d_in, const int* in_sizes, int n_in,
                              void* d_out, int out_size, void* d_ws, size_t ws_size,
                              hipStream_t stream) {
  (void)in_sizes; (void)n_in; (void)out_size; (void)ws_size;
  const float* ctx   = (const float*)d_in[0];
  const float* que   = (const float*)d_in[1];
  const float* cmask = (const float*)d_in[2];
  const float* qmask = (const float*)d_in[3];
  const float* ln_g  = (const float*)d_in[4];
  const float* ln_b  = (const float*)d_in[5];
  const float* dw_w  = (const float*)d_in[6];
  const float* dw_b  = (const float*)d_in[7];
  const float* pw_w  = (const float*)d_in[8];
  const float* pw_b  = (const float*)d_in[9];
  const float* Wq    = (const float*)d_in[10];
  const float* bq    = (const float*)d_in[11];
  const float* Wk    = (const float*)d_in[12];
  const float* bk    = (const float*)d_in[13];
  const float* Wv    = (const float*)d_in[14];
  const float* bv    = (const float*)d_in[15];
  const float* Wo    = (const float*)d_in[16];
  const float* bo    = (const float*)d_in[17];
  const float* Wfc   = (const float*)d_in[18];
  const float* bfc   = (const float*)d_in[19];
  const float* cq_wc = (const float*)d_in[20];
  const float* cq_wq = (const float*)d_in[21];
  const float* cq_wm = (const float*)d_in[22];
  const float* cq_b  = (const float*)d_in[23];
  float* out = (float*)d_out;
  float* ws = (float*)d_ws;

  float* Cb   = ws;
  float* Qb   = Cb + SZ_C;
  float* t1C  = Qb + SZ_Q;
  float* t1Q  = t1C + SZ_C;
  float* t2C  = t1Q + SZ_Q;
  float* t2Q  = t2C + SZ_C;
  float* t3C  = t2Q + SZ_Q;
  float* t3Q  = t3C + SZ_C;
  float* t4C  = t3Q + SZ_Q;
  float* t4Q  = t4C + SZ_C;
  float* mu0  = t4Q + SZ_Q;
  float* inv0 = mu0 + SSTAT;
  float* mu1  = inv0 + SSTAT;
  float* inv1 = mu1 + SSTAT;
  float* Wcan = inv1 + SSTAT;

  k_transposeW<<<(9 * 16384 + 255) / 256, 256, 0, stream>>>(pw_w, Wo, Wfc, Wq, Wk, Wv, Wcan);
  k_pestats<<<512, 256, 0, stream>>>(ctx, que, Cb, Qb, mu0, inv0);

  // conv layers: fused LN+dwconv+pwGEMM+relu+residual+stats. Ping-pong Cb <-> t1.
  for (int i = 0; i < NC; ++i) {
    const float* inC = (i & 1) ? t1C : Cb;
    const float* inQ = (i & 1) ? t1Q : Qb;
    float* oC = (i & 1) ? Cb : t1C;
    float* oQ = (i & 1) ? Qb : t1Q;
    const float* mI = (i & 1) ? mu1 : mu0;
    const float* iI = (i & 1) ? inv1 : inv0;
    float* mO = (i & 1) ? mu0 : mu1;
    float* iO = (i & 1) ? inv0 : inv1;
    k_convgemm<<<512, 256, 0, stream>>>(inC, inQ, oC, oQ,
                                        Wcan + (size_t)i * 16384, pw_b + (size_t)i * DD,
                                        dw_w + (size_t)i * DD * KW, dw_b + (size_t)i * DD,
                                        mI, iI, mO, iO, ln_g, ln_b);
  }
  // after 4 layers, result in Cb with stats in mu0/inv0.
  k_gemm_qkv<<<1536, 256, 0, stream>>>(Cb, Qb, t1C, t1Q, t2C, t2Q, t3C, t3Q,
                                       Wcan, bq, bk, bv, mu0, inv0, ln_g, ln_b);
  k_attn2<<<1536, 256, 0, stream>>>(t1C, t2C, t3C, t1Q, t2Q, t3Q, cmask, qmask, t4C, t4Q);
  // Wo projection: +residual into Cb, stats -> mu1/inv1
  k_gemm64<0, 1, 1><<<512, 256, 0, stream>>>(t4C, t4Q, Cb, Qb, Wcan + 4 * 16384, bo,
                                             mu0, inv0, mu1, inv1, ln_g, ln_b);
  // FFN: LN(mu1) + GEMM + residual, in-place on Cb
  k_gemm64<1, 1, 0><<<512, 256, 0, stream>>>(Cb, Qb, Cb, Qb, Wcan + 5 * 16384, bfc,
                                             mu1, inv1, mu0, inv0, ln_g, ln_b);

  // ---- context-query attention ----
  float* C2  = t1C;
  float* Q2  = t1Q;
  float* S   = t2C;
  float* Sr  = t2C + 1638400;
  float* Scb = t3C;
  float* Uu  = t2Q;
  float* cd  = t3Q;
  float* qd  = t4Q;

  k_prep<<<3953, 256, 0, stream>>>(Cb, Qb, C2, Q2, cq_wc, cq_wq, cd, qd);
  k_S<<<(BB * NN * MM + 255) / 256, 256, 0, stream>>>(C2, Q2, cd, qd, cq_wm, cq_b, S);
  k_smax<<<BB * MM + BB * NN, 64, 0, stream>>>(S, Sr, Scb, cmask, qmask);
  k_U<<<(BB * MM * 32 + 255) / 256, 256, 0, stream>>>(Scb, C2, Uu);
  k_ABtF<<<448, 256, 0, stream>>>(Sr, Q2, Uu, C2, out);
}

// Round 6
// 718.181 us; speedup vs baseline: 15.0074x; 1.0046x over previous
//
#include <hip/hip_runtime.h>
#include <math.h>

#define BB 64
#define DD 128
#define NN 400
#define MM 50
#define HH 8
#define KDIM 16
#define NC 4
#define KW 7
#define CH 200   // attention key-chunk: LDS 26.4 KB -> 6 blocks/CU

#define SZ_C (BB * DD * NN)   // 3,276,800
#define SZ_Q (BB * DD * MM)   //   409,600
#define SSTAT (BB * NN + BB * MM)  // 28,800; q stats at offset BB*NN

// ---------------- canonical weight transpose: Wcan[m][d][e] ----------------
__global__ void k_transposeW(const float* __restrict__ pw_w, const float* __restrict__ Wo,
                             const float* __restrict__ Wfc, const float* __restrict__ Wq,
                             const float* __restrict__ Wk, const float* __restrict__ Wv,
                             float* __restrict__ Wcan) {
  int idx = blockIdx.x * 256 + threadIdx.x;
  if (idx >= 9 * 16384) return;
  int m = idx >> 14;
  int r = idx & 16383;
  int d = r >> 7, e = r & 127;
  float v;
  if (m < 4) v = pw_w[m * 16384 + e * 128 + d];
  else if (m == 4) v = Wo[d * 128 + e];
  else if (m == 5) v = Wfc[e * 128 + d];
  else {
    const float* W = (m == 6) ? Wq : (m == 7) ? Wk : Wv;
    v = W[((e >> 4) * 128 + d) * 16 + (e & 15)];
  }
  Wcan[idx] = v;
}

// ---------------- fused PE add + LN stats ----------------
__global__ void k_pestats(const float* __restrict__ xC, const float* __restrict__ xQ,
                          float* __restrict__ yC, float* __restrict__ yQ,
                          float* __restrict__ mu, float* __restrict__ inv) {
  int blk = blockIdx.x;
  const float* x; float* y; int L, l0, b, soff;
  if (blk < 448) { b = blk / 7; l0 = (blk % 7) * 64; x = xC; y = yC; L = NN; soff = 0; }
  else { b = blk - 448; l0 = 0; x = xQ; y = yQ; L = MM; soff = BB * NN; }
  int tid = threadIdx.x;
  int ll = tid & 63;
  int dq = tid >> 6;
  int l = l0 + ll;
  __shared__ float s_sum[4][64], s_sq[4][64];
  float sum = 0.f, sq = 0.f;
  if (l < L) {
    const float* px = x + (size_t)b * DD * L + l;
    float* py = y + (size_t)b * DD * L + l;
    for (int d = dq * 32; d < dq * 32 + 32; ++d) {
      int de = d & ~1;
      float freq = __expf((float)de * (-9.210340371976184f / 128.0f));
      float ph = (d & 1) ? 1.5707963267948966f : 0.0f;
      float v = px[(size_t)d * L] + sinf((float)l * freq + ph);
      py[(size_t)d * L] = v;
      sum += v; sq += v * v;
    }
  }
  s_sum[dq][ll] = sum; s_sq[dq][ll] = sq;
  __syncthreads();
  if (dq == 0 && l < L) {
    float ts = s_sum[0][ll] + s_sum[1][ll] + s_sum[2][ll] + s_sum[3][ll];
    float tq = s_sq[0][ll] + s_sq[1][ll] + s_sq[2][ll] + s_sq[3][ll];
    float m = ts * (1.0f / 128.0f);
    float var = (tq - 128.0f * m * m) * (1.0f / 127.0f);
    float sd = sqrtf(fmaxf(var, 0.f));
    mu[soff + b * L + l] = m;
    inv[soff + b * L + l] = 1.0f / (sd + 1e-6f);
  }
}

// ---------------- fused conv layer, 64-col tiles (512 blocks = 2/CU) ----------------
__global__ __launch_bounds__(256, 2) void k_convgemm(
    const float* __restrict__ xC, const float* __restrict__ xQ,
    float* __restrict__ outC, float* __restrict__ outQ,
    const float* __restrict__ Wc, const float* __restrict__ pwb,
    const float* __restrict__ dww, const float* __restrict__ dwb,
    const float* __restrict__ muI, const float* __restrict__ invI,
    float* __restrict__ muO, float* __restrict__ invO,
    const float* __restrict__ g, const float* __restrict__ beta) {
  int blk = blockIdx.x;
  int b = blk >> 3, tile = blk & 7;
  const float* x; float* out; int L, l0, soff;
  if (tile < 7) { x = xC; out = outC; L = NN; l0 = tile * 64; soff = 0; }
  else { x = xQ; out = outQ; L = MM; l0 = 0; soff = BB * NN; }
  __shared__ float Wl[32 * 128];
  __shared__ float Xl[32 * 64];
  __shared__ float Sm[70], Si[70];   // stats halo [l0-3, l0+67)
  int tid = threadIdx.x;
  const float* xb = x + (size_t)b * DD * L;
  for (int t = tid; t < 70; t += 256) {
    int gl = l0 + t - 3;
    bool ok = (gl >= 0 && gl < L);
    Sm[t] = ok ? muI[soff + b * L + gl] : 0.f;
    Si[t] = ok ? invI[soff + b * L + gl] : 0.f;
  }
  float acc[8][4];
  #pragma unroll
  for (int i = 0; i < 8; ++i)
    #pragma unroll
    for (int j = 0; j < 4; ++j) acc[i][j] = 0.f;
  __syncthreads();
  for (int kc = 0; kc < 4; ++kc) {
    int d0 = kc * 32;
    #pragma unroll
    for (int i = 0; i < 4; ++i) {
      int idx = i * 256 + tid;
      ((float4*)Wl)[idx] = ((const float4*)Wc)[(size_t)d0 * 32 + idx];
    }
    #pragma unroll
    for (int r = 0; r < 2; ++r) {
      int k = r * 16 + (tid >> 4);
      int d = d0 + k;
      int c0 = (tid & 15) * 4;
      const float* xrow = xb + (size_t)d * L;
      float gd = g[d], bd = beta[d];
      float wv[7];
      #pragma unroll
      for (int u = 0; u < 7; ++u) wv[u] = dww[d * 7 + u];
      float dbv = dwb[d];
      float xw[10];
      int gbase = l0 + c0 - 3;
      if (gbase >= 1 && gbase + 11 <= L && (((unsigned)(d * L + gbase - 1)) & 3u) == 0u) {
        const float4* p = (const float4*)&xrow[gbase - 1];
        float4 A = p[0], Bv = p[1], Cv = p[2];
        float xr[12] = {A.x, A.y, A.z, A.w, Bv.x, Bv.y, Bv.z, Bv.w, Cv.x, Cv.y, Cv.z, Cv.w};
        #pragma unroll
        for (int s = 0; s < 10; ++s)
          xw[s] = gd * (xr[s + 1] - Sm[c0 + s]) * Si[c0 + s] + bd;
      } else {
        #pragma unroll
        for (int s = 0; s < 10; ++s) {
          int gl = gbase + s;
          float v = 0.f;
          if (gl >= 0 && gl < L)
            v = gd * (xrow[gl] - Sm[c0 + s]) * Si[c0 + s] + bd;
          xw[s] = v;
        }
      }
      float4 o;
      o.x = dbv; o.y = dbv; o.z = dbv; o.w = dbv;
      #pragma unroll
      for (int u = 0; u < 7; ++u) {
        o.x += wv[u] * xw[u];
        o.y += wv[u] * xw[u + 1];
        o.z += wv[u] * xw[u + 2];
        o.w += wv[u] * xw[u + 3];
      }
      *(float4*)&Xl[k * 64 + c0] = o;
    }
    __syncthreads();
    int e0 = (tid >> 4) * 8, cq = (tid & 15) * 4;
    for (int k = 0; k < 32; ++k) {
      const float4* wp = (const float4*)&Wl[k * 128 + e0];
      float4 w0 = wp[0], w1 = wp[1];
      float4 xv = *(const float4*)&Xl[k * 64 + cq];
      float we[8] = {w0.x, w0.y, w0.z, w0.w, w1.x, w1.y, w1.z, w1.w};
      float xe[4] = {xv.x, xv.y, xv.z, xv.w};
      #pragma unroll
      for (int i = 0; i < 8; ++i)
        #pragma unroll
        for (int j = 0; j < 4; ++j) acc[i][j] += we[i] * xe[j];
    }
    __syncthreads();
  }
  int e0 = (tid >> 4) * 8, cq = (tid & 15) * 4;
  float ssum[4], ssq[4];
  #pragma unroll
  for (int j = 0; j < 4; ++j) { ssum[j] = 0.f; ssq[j] = 0.f; }
  #pragma unroll
  for (int i = 0; i < 8; ++i) {
    float bi = pwb[e0 + i];
    float* po = out + ((size_t)b * DD + e0 + i) * L;
    const float* pr = xb + (size_t)(e0 + i) * L;
    #pragma unroll
    for (int j = 0; j < 4; ++j) {
      int l = l0 + cq + j;
      if (l < L) {
        float v = fmaxf(acc[i][j] + bi, 0.f) + pr[l];
        po[l] = v;
        ssum[j] += v; ssq[j] += v * v;
      }
    }
  }
  int grp = tid >> 4;
  #pragma unroll
  for (int j = 0; j < 4; ++j) {
    Xl[grp * 64 + cq + j] = ssum[j];
    Wl[grp * 64 + cq + j] = ssq[j];
  }
  __syncthreads();
  if (tid < 64) {
    int l = l0 + tid;
    if (l < L) {
      float ts = 0.f, tq = 0.f;
      #pragma unroll
      for (int gg = 0; gg < 16; ++gg) { ts += Xl[gg * 64 + tid]; tq += Wl[gg * 64 + tid]; }
      float m = ts * (1.0f / 128.0f);
      float var = (tq - 128.0f * m * m) * (1.0f / 127.0f);
      float sd = sqrtf(fmaxf(var, 0.f));
      muO[soff + b * L + l] = m;
      invO[soff + b * L + l] = 1.0f / (sd + 1e-6f);
    }
  }
}

// ---------------- 128x64 GEMM tiles, 512 blocks ----------------
template <int LNF, int ACT, int STATS>
__global__ __launch_bounds__(256) void k_gemm64(
    const float* __restrict__ xC, const float* __restrict__ xQ,
    float* __restrict__ outC, float* __restrict__ outQ,
    const float* __restrict__ Wc, const float* __restrict__ bias,
    const float* __restrict__ mu, const float* __restrict__ inv,
    float* __restrict__ muO, float* __restrict__ invO,
    const float* __restrict__ g, const float* __restrict__ beta) {
  int blk = blockIdx.x;
  int b = blk >> 3, tile = blk & 7;
  const float* x; float* out; int L, l0, soff;
  if (tile < 7) { x = xC; out = outC; L = NN; l0 = tile * 64; soff = 0; }
  else { x = xQ; out = outQ; L = MM; l0 = 0; soff = BB * NN; }
  __shared__ float Wl[32 * 128];
  __shared__ float Xl[32 * 64];
  int tid = threadIdx.x;
  float acc[8][4];
  #pragma unroll
  for (int i = 0; i < 8; ++i)
    #pragma unroll
    for (int j = 0; j < 4; ++j) acc[i][j] = 0.f;
  const float* xb = x + (size_t)b * DD * L;
  const float* pmu = mu + soff + b * L;
  const float* pin = inv + soff + b * L;
  for (int kc = 0; kc < 4; ++kc) {
    int d0 = kc * 32;
    #pragma unroll
    for (int i = 0; i < 4; ++i) {
      int idx = i * 256 + tid;
      ((float4*)Wl)[idx] = ((const float4*)Wc)[(size_t)d0 * 32 + idx];
    }
    #pragma unroll
    for (int t = 0; t < 8; ++t) {
      int idx = t * 256 + tid;
      int k = idx >> 6, l = idx & 63;
      float v = 0.f;
      int gl = l0 + l;
      if (gl < L) {
        v = xb[(size_t)(d0 + k) * L + gl];
        if (LNF) v = g[d0 + k] * (v - pmu[gl]) * pin[gl] + beta[d0 + k];
      }
      Xl[idx] = v;
    }
    __syncthreads();
    int e0 = (tid >> 4) * 8, cq = (tid & 15) * 4;
    for (int k = 0; k < 32; ++k) {
      const float4* wp = (const float4*)&Wl[k * 128 + e0];
      float4 w0 = wp[0], w1 = wp[1];
      float4 xv = *(const float4*)&Xl[k * 64 + cq];
      float we[8] = {w0.x, w0.y, w0.z, w0.w, w1.x, w1.y, w1.z, w1.w};
      float xe[4] = {xv.x, xv.y, xv.z, xv.w};
      #pragma unroll
      for (int i = 0; i < 8; ++i)
        #pragma unroll
        for (int j = 0; j < 4; ++j) acc[i][j] += we[i] * xe[j];
    }
    __syncthreads();
  }
  int e0 = (tid >> 4) * 8, cq = (tid & 15) * 4;
  float ssum[4], ssq[4];
  #pragma unroll
  for (int j = 0; j < 4; ++j) { ssum[j] = 0.f; ssq[j] = 0.f; }
  #pragma unroll
  for (int i = 0; i < 8; ++i) {
    float bi = bias[e0 + i];
    float* po = out + ((size_t)b * DD + e0 + i) * L;
    #pragma unroll
    for (int j = 0; j < 4; ++j) {
      int l = l0 + cq + j;
      if (l < L) {
        float v = acc[i][j] + bi;
        if (ACT != 0) v += po[l];
        po[l] = v;
        if (STATS) { ssum[j] += v; ssq[j] += v * v; }
      }
    }
  }
  if (STATS) {
    int grp = tid >> 4;
    #pragma unroll
    for (int j = 0; j < 4; ++j) {
      Xl[grp * 64 + cq + j] = ssum[j];
      Wl[grp * 64 + cq + j] = ssq[j];
    }
    __syncthreads();
    if (tid < 64) {
      int l = l0 + tid;
      if (l < L) {
        float ts = 0.f, tq = 0.f;
        #pragma unroll
        for (int gg = 0; gg < 16; ++gg) { ts += Xl[gg * 64 + tid]; tq += Wl[gg * 64 + tid]; }
        float m = ts * (1.0f / 128.0f);
        float var = (tq - 128.0f * m * m) * (1.0f / 127.0f);
        float sd = sqrtf(fmaxf(var, 0.f));
        muO[soff + b * L + l] = m;
        invO[soff + b * L + l] = 1.0f / (sd + 1e-6f);
      }
    }
  }
}

// ---------------- fused QKV GEMM: 3 x 512 blocks ----------------
__global__ __launch_bounds__(256) void k_gemm_qkv(
    const float* __restrict__ xC, const float* __restrict__ xQ,
    float* __restrict__ o1C, float* __restrict__ o1Q,
    float* __restrict__ o2C, float* __restrict__ o2Q,
    float* __restrict__ o3C, float* __restrict__ o3Q,
    const float* __restrict__ Wcan,
    const float* __restrict__ bq, const float* __restrict__ bk, const float* __restrict__ bv,
    const float* __restrict__ mu, const float* __restrict__ inv,
    const float* __restrict__ g, const float* __restrict__ beta) {
  int blk0 = blockIdx.x;
  int grp = blk0 >> 9;
  int blk = blk0 & 511;
  const float* Wc = Wcan + (size_t)(6 + grp) * 16384;
  const float* bias = (grp == 0) ? bq : (grp == 1) ? bk : bv;
  float* oC = (grp == 0) ? o1C : (grp == 1) ? o2C : o3C;
  float* oQ = (grp == 0) ? o1Q : (grp == 1) ? o2Q : o3Q;
  int b = blk >> 3, tile = blk & 7;
  const float* x; float* out; int L, l0, soff;
  if (tile < 7) { x = xC; out = oC; L = NN; l0 = tile * 64; soff = 0; }
  else { x = xQ; out = oQ; L = MM; l0 = 0; soff = BB * NN; }
  __shared__ float Wl[32 * 128];
  __shared__ float Xl[32 * 64];
  int tid = threadIdx.x;
  float acc[8][4];
  #pragma unroll
  for (int i = 0; i < 8; ++i)
    #pragma unroll
    for (int j = 0; j < 4; ++j) acc[i][j] = 0.f;
  const float* xb = x + (size_t)b * DD * L;
  const float* pmu = mu + soff + b * L;
  const float* pin = inv + soff + b * L;
  for (int kc = 0; kc < 4; ++kc) {
    int d0 = kc * 32;
    #pragma unroll
    for (int i = 0; i < 4; ++i) {
      int idx = i * 256 + tid;
      ((float4*)Wl)[idx] = ((const float4*)Wc)[(size_t)d0 * 32 + idx];
    }
    #pragma unroll
    for (int t = 0; t < 8; ++t) {
      int idx = t * 256 + tid;
      int k = idx >> 6, l = idx & 63;
      float v = 0.f;
      int gl = l0 + l;
      if (gl < L) {
        v = xb[(size_t)(d0 + k) * L + gl];
        v = g[d0 + k] * (v - pmu[gl]) * pin[gl] + beta[d0 + k];
      }
      Xl[idx] = v;
    }
    __syncthreads();
    int e0 = (tid >> 4) * 8, cq = (tid & 15) * 4;
    for (int k = 0; k < 32; ++k) {
      const float4* wp = (const float4*)&Wl[k * 128 + e0];
      float4 w0 = wp[0], w1 = wp[1];
      float4 xv = *(const float4*)&Xl[k * 64 + cq];
      float we[8] = {w0.x, w0.y, w0.z, w0.w, w1.x, w1.y, w1.z, w1.w};
      float xe[4] = {xv.x, xv.y, xv.z, xv.w};
      #pragma unroll
      for (int i = 0; i < 8; ++i)
        #pragma unroll
        for (int j = 0; j < 4; ++j) acc[i][j] += we[i] * xe[j];
    }
    __syncthreads();
  }
  int e0 = (tid >> 4) * 8, cq = (tid & 15) * 4;
  #pragma unroll
  for (int i = 0; i < 8; ++i) {
    float bi = bias[e0 + i];
    float* po = out + ((size_t)b * DD + e0 + i) * L;
    #pragma unroll
    for (int j = 0; j < 4; ++j) {
      int l = l0 + cq + j;
      if (l < L) po[l] = acc[i][j] + bi;
    }
  }
}

// ---------------- attention: key-chunked LDS (CH=200 -> 26.4 KB, 6 blocks/CU) ----------------
// Online softmax carries m/ls/acc across chunks. All threads participate in
// staging every chunk (no early exit); barriers are outside divergent code.
__global__ __launch_bounds__(256) void k_attn2(
    const float* __restrict__ qC, const float* __restrict__ kC, const float* __restrict__ vC,
    const float* __restrict__ qQ, const float* __restrict__ kQ, const float* __restrict__ vQ,
    const float* __restrict__ cmask, const float* __restrict__ qmask,
    float* __restrict__ oC, float* __restrict__ oQ) {
  int blk = blockIdx.x;
  const float *qp, *kp, *vp, *mk; float* op; int L, b, h, q0, qcnt;
  if (blk < 1024) {
    b = blk >> 4; h = (blk >> 1) & 7; int half = blk & 1;
    qp = qC; kp = kC; vp = vC; mk = cmask; op = oC; L = NN;
    q0 = half * 256; qcnt = half ? (NN - 256) : 256;
  } else {
    int bb = blk - 1024; b = bb >> 3; h = bb & 7;
    qp = qQ; kp = kQ; vp = vQ; mk = qmask; op = oQ; L = MM;
    q0 = 0; qcnt = MM;
  }
  __shared__ float Kl[CH * KDIM];
  __shared__ float Vl[CH * KDIM];
  __shared__ float Ml[CH + 8];
  int tid = threadIdx.x;
  size_t base = ((size_t)b * DD + h * KDIM) * L;
  bool act = tid < qcnt;
  int i = q0 + tid;
  float q[KDIM];
  #pragma unroll
  for (int t = 0; t < KDIM; ++t)
    q[t] = act ? qp[base + (size_t)t * L + i] * 0.25f : 0.f;
  float m = -1e30f, ls = 0.f;
  float acc[KDIM];
  #pragma unroll
  for (int t = 0; t < KDIM; ++t) acc[t] = 0.f;

  for (int c0 = 0; c0 < L; c0 += CH) {
    int ch = L - c0; if (ch > CH) ch = CH;
    int chp = (ch + 7) & ~7;   // 200 or 56
    // stage chunk (all threads)
    const float* kpc = kp + base + c0;
    const float* vpc = vp + base + c0;
    for (int idx = tid; idx < KDIM * ch; idx += 256) {
      int t = idx / ch, j = idx - t * ch;
      Kl[j * KDIM + t] = kpc[(size_t)t * L + j];
      Vl[j * KDIM + t] = vpc[(size_t)t * L + j];
    }
    for (int idx = tid; idx < (chp - ch) * KDIM; idx += 256) {
      int j = ch + (idx >> 4), t = idx & 15;
      Kl[j * KDIM + t] = 0.f; Vl[j * KDIM + t] = 0.f;
    }
    for (int j = tid; j < chp; j += 256)
      Ml[j] = (j < ch) ? -1e30f * (1.0f - mk[b * L + c0 + j]) : -1e30f;
    __syncthreads();
    if (act) {
      for (int j0 = 0; j0 < chp; j0 += 8) {
        const float4* mp = (const float4*)&Ml[j0];
        float4 ma0 = mp[0], ma1 = mp[1];
        float mav[8] = {ma0.x, ma0.y, ma0.z, ma0.w, ma1.x, ma1.y, ma1.z, ma1.w};
        float s[8];
        #pragma unroll
        for (int jj = 0; jj < 8; ++jj) {
          const float4* kf = (const float4*)&Kl[(j0 + jj) * KDIM];
          float4 k0 = kf[0], k1 = kf[1], k2 = kf[2], k3 = kf[3];
          float da = q[0] * k0.x + q[1] * k0.y + q[2] * k0.z + q[3] * k0.w
                   + q[4] * k1.x + q[5] * k1.y + q[6] * k1.z + q[7] * k1.w;
          float db = q[8] * k2.x + q[9] * k2.y + q[10] * k2.z + q[11] * k2.w
                   + q[12] * k3.x + q[13] * k3.y + q[14] * k3.z + q[15] * k3.w;
          s[jj] = da + db + mav[jj];
        }
        float cm = s[0];
        #pragma unroll
        for (int jj = 1; jj < 8; ++jj) cm = fmaxf(cm, s[jj]);
        if (cm > m) {  // exact: skipped branch would multiply by exp(0)=1
          float sc = __expf(m - cm);
          ls *= sc;
          #pragma unroll
          for (int t = 0; t < KDIM; ++t) acc[t] *= sc;
          m = cm;
        }
        #pragma unroll
        for (int jj = 0; jj < 8; ++jj) {
          float p = __expf(s[jj] - m);
          ls += p;
          const float4* vf = (const float4*)&Vl[(j0 + jj) * KDIM];
          float4 v0 = vf[0], v1 = vf[1], v2 = vf[2], v3 = vf[3];
          acc[0] += p * v0.x;  acc[1] += p * v0.y;  acc[2] += p * v0.z;  acc[3] += p * v0.w;
          acc[4] += p * v1.x;  acc[5] += p * v1.y;  acc[6] += p * v1.z;  acc[7] += p * v1.w;
          acc[8] += p * v2.x;  acc[9] += p * v2.y;  acc[10] += p * v2.z; acc[11] += p * v2.w;
          acc[12] += p * v3.x; acc[13] += p * v3.y; acc[14] += p * v3.z; acc[15] += p * v3.w;
        }
      }
    }
    __syncthreads();  // chunk compute done before next stage overwrites LDS
  }
  if (act) {
    float invl = 1.0f / ls;
    #pragma unroll
    for (int t = 0; t < KDIM; ++t)
      op[base + (size_t)t * L + i] = acc[t] * invl;
  }
}

// ---------------- fused prep: tiled transposes + dotD ----------------
__global__ void k_prep(const float* __restrict__ Cb, const float* __restrict__ Qb,
                       float* __restrict__ C2, float* __restrict__ Q2,
                       const float* __restrict__ wc, const float* __restrict__ wq,
                       float* __restrict__ cd, float* __restrict__ qd) {
  int blk = blockIdx.x, tid = threadIdx.x;
  if (blk < 3840) {
    const float* X; float* Y; int L, rem;
    if (blk < 3328) { X = Cb; Y = C2; L = NN; rem = blk; }
    else { X = Qb; Y = Q2; L = MM; rem = blk - 3328; }
    int ntl = (L + 31) / 32;
    int b = rem / (4 * ntl);
    int r2 = rem % (4 * ntl);
    int d0 = (r2 / ntl) * 32;
    int l0 = (r2 % ntl) * 32;
    __shared__ float T[32][33];
    int c = tid & 31, r8 = tid >> 5;
    const float* xb = X + (size_t)b * DD * L;
    #pragma unroll
    for (int k = 0; k < 4; ++k) {
      int r = r8 + k * 8;
      int l = l0 + c;
      T[r][c] = (l < L) ? xb[(size_t)(d0 + r) * L + l] : 0.f;
    }
    __syncthreads();
    float* yb = Y + (size_t)b * L * DD;
    #pragma unroll
    for (int k = 0; k < 4; ++k) {
      int rr = r8 + k * 8;
      int l = l0 + rr;
      if (l < L) yb[(size_t)l * DD + d0 + c] = T[c][rr];
    }
  } else if (blk < 3940) {
    int idx = (blk - 3840) * 256 + tid;
    if (idx < BB * NN) {
      int l = idx % NN, b = idx / NN;
      const float* px = Cb + (size_t)b * DD * NN + l;
      float acc = 0.f;
      for (int d = 0; d < DD; ++d) acc += px[(size_t)d * NN] * wc[d];
      cd[idx] = acc;
    }
  } else {
    int idx = (blk - 3940) * 256 + tid;
    if (idx < BB * MM) {
      int l = idx % MM, b = idx / MM;
      const float* px = Qb + (size_t)b * DD * MM + l;
      float acc = 0.f;
      for (int d = 0; d < DD; ++d) acc += px[(size_t)d * MM] * wq[d];
      qd[idx] = acc;
    }
  }
}

// ---------------- S[b,n,m] trilinear ----------------
__global__ void k_S(const float* __restrict__ C2, const float* __restrict__ Q2,
                    const float* __restrict__ cd, const float* __restrict__ qd,
                    const float* __restrict__ wm, const float* __restrict__ bias,
                    float* __restrict__ S) {
  int idx = blockIdx.x * 256 + threadIdx.x;
  if (idx >= BB * NN * MM) return;
  int mcol = idx % MM;
  int n = (idx / MM) % NN;
  int b = idx / (MM * NN);
  const float4* pc = (const float4*)(C2 + ((size_t)b * NN + n) * DD);
  const float4* pq = (const float4*)(Q2 + ((size_t)b * MM + mcol) * DD);
  const float4* pw = (const float4*)wm;
  float a0 = 0.f, a1 = 0.f;
  #pragma unroll 4
  for (int d4 = 0; d4 < 32; d4 += 2) {
    float4 c0 = pc[d4], w0 = pw[d4], q0 = pq[d4];
    float4 c1 = pc[d4 + 1], w1 = pw[d4 + 1], q1 = pq[d4 + 1];
    a0 += (c0.x * w0.x) * q0.x + (c0.y * w0.y) * q0.y + (c0.z * w0.z) * q0.z + (c0.w * w0.w) * q0.w;
    a1 += (c1.x * w1.x) * q1.x + (c1.y * w1.y) * q1.y + (c1.z * w1.z) * q1.z + (c1.w * w1.w) * q1.w;
  }
  S[idx] = a0 + a1 + cd[b * NN + n] + qd[b * MM + mcol] + bias[0];
}

// ---------------- merged softmaxes ----------------
__global__ void k_smax(const float* __restrict__ S, float* __restrict__ Sr,
                       float* __restrict__ Sc, const float* __restrict__ cmask,
                       const float* __restrict__ qmask) {
  int blk = blockIdx.x;
  int tid = threadIdx.x;
  if (blk < BB * MM) {
    int b = blk / MM;
    int mcol = blk % MM;
    float vals[7];
    float mx = -1e30f;
    #pragma unroll
    for (int c = 0; c < 7; ++c) {
      int n = tid + c * 64;
      float s = -1e30f;
      if (n < NN)
        s = S[((size_t)b * NN + n) * MM + mcol] - 1e30f * (1.0f - cmask[b * NN + n]);
      vals[c] = s;
      mx = fmaxf(mx, s);
    }
    #pragma unroll
    for (int off = 1; off < 64; off <<= 1) mx = fmaxf(mx, __shfl_xor(mx, off));
    float sum = 0.f;
    #pragma unroll
    for (int c = 0; c < 7; ++c) { vals[c] = __expf(vals[c] - mx); sum += vals[c]; }
    #pragma unroll
    for (int off = 1; off < 64; off <<= 1) sum += __shfl_xor(sum, off);
    float inv = 1.0f / sum;
    #pragma unroll
    for (int c = 0; c < 7; ++c) {
      int n = tid + c * 64;
      if (n < NN) Sc[((size_t)b * NN + n) * MM + mcol] = vals[c] * inv;
    }
  } else {
    int bn = blk - BB * MM;
    int b = bn / NN;
    float s = -1e30f;
    if (tid < MM)
      s = S[(size_t)bn * MM + tid] - 1e30f * (1.0f - qmask[b * MM + tid]);
    float mx = s;
    #pragma unroll
    for (int off = 1; off < 64; off <<= 1) mx = fmaxf(mx, __shfl_xor(mx, off));
    float e = (tid < MM) ? __expf(s - mx) : 0.f;
    float sum = e;
    #pragma unroll
    for (int off = 1; off < 64; off <<= 1) sum += __shfl_xor(sum, off);
    if (tid < MM) Sr[(size_t)bn * MM + tid] = e / sum;
  }
}

// ---------------- U[b,m,d] = sum_k Sc[b,k,m]*C2[b,k,d] ----------------
__global__ void k_U(const float* __restrict__ Sc, const float* __restrict__ C2,
                    float* __restrict__ U) {
  int idx = blockIdx.x * 256 + threadIdx.x;
  if (idx >= BB * MM * 32) return;
  int d4 = idx & 31;
  int rest = idx >> 5;
  int mcol = rest % MM;
  int b = rest / MM;
  const float* psc = Sc + (size_t)b * NN * MM + mcol;
  const float4* pc2 = (const float4*)(C2 + (size_t)b * NN * DD) + d4;
  float4 acc = {0.f, 0.f, 0.f, 0.f};
  #pragma unroll 4
  for (int kk = 0; kk < NN; ++kk) {
    float s = psc[(size_t)kk * MM];
    float4 c = pc2[(size_t)kk * 32];
    acc.x += s * c.x; acc.y += s * c.y; acc.z += s * c.z; acc.w += s * c.w;
  }
  ((float4*)U)[idx] = acc;
}

// ---------------- fused A/Bt + final concat; LDS-staged Q2/Uu/Sr ----------------
__global__ __launch_bounds__(256) void k_ABtF(
    const float* __restrict__ Sr, const float* __restrict__ Q2,
    const float* __restrict__ Uu, const float* __restrict__ C2,
    float* __restrict__ out) {
  int blk = blockIdx.x;
  int b = blk / 7, nt = blk % 7;
  int n0 = nt * 64;
  int nv = NN - n0; if (nv > 64) nv = 64;
  __shared__ float Ql[MM * 128];
  __shared__ float Ul[MM * 128];
  __shared__ float Sl[64 * MM];
  int tid = threadIdx.x;
  const float4* q4 = (const float4*)(Q2 + (size_t)b * MM * DD);
  const float4* u4 = (const float4*)(Uu + (size_t)b * MM * DD);
  for (int i = tid; i < MM * 32; i += 256) {
    ((float4*)Ql)[i] = q4[i];
    ((float4*)Ul)[i] = u4[i];
  }
  for (int i = tid; i < 64 * MM; i += 256) {
    int n = i / MM;
    Sl[i] = (n < nv) ? Sr[((size_t)b * NN + n0 + n) * MM + (i - n * MM)] : 0.f;
  }
  __syncthreads();
  int n = tid >> 2;
  if (n >= nv) return;
  int d04 = (tid & 3) * 8;
  float4 accA[8], accB[8];
  #pragma unroll
  for (int r = 0; r < 8; ++r) {
    accA[r] = {0.f, 0.f, 0.f, 0.f};
    accB[r] = {0.f, 0.f, 0.f, 0.f};
  }
  const float* sp = &Sl[n * MM];
  for (int m = 0; m < MM; ++m) {
    float s = sp[m];
    const float4* qp = (const float4*)&Ql[m * 128] + d04;
    const float4* up = (const float4*)&Ul[m * 128] + d04;
    #pragma unroll
    for (int r = 0; r < 8; ++r) {
      float4 q = qp[r], u = up[r];
      accA[r].x += s * q.x; accA[r].y += s * q.y; accA[r].z += s * q.z; accA[r].w += s * q.w;
      accB[r].x += s * u.x; accB[r].y += s * u.y; accB[r].z += s * u.z; accB[r].w += s * u.w;
    }
  }
  int gn = n0 + n;
  const float4* c4 = (const float4*)(C2 + ((size_t)b * NN + gn) * DD) + d04;
  float4* po = (float4*)(out + (size_t)(b * NN + gn) * 512);
  #pragma unroll
  for (int r = 0; r < 8; ++r) {
    float4 c = c4[r];
    float4 a = accA[r], bt = accB[r];
    po[d04 + r] = c;
    po[32 + d04 + r] = a;
    float4 ca = {c.x * a.x, c.y * a.y, c.z * a.z, c.w * a.w};
    po[64 + d04 + r] = ca;
    float4 cb = {c.x * bt.x, c.y * bt.y, c.z * bt.z, c.w * bt.w};
    po[96 + d04 + r] = cb;
  }
}

extern "C" void kernel_launch(void* const* d_in, const int* in_sizes, int n_in,
                              void* d_out, int out_size, void* d_ws, size_t ws_size,
                              hipStream_t stream) {
  (void)in_sizes; (void)n_in; (void)out_size; (void)ws_size;
  const float* ctx   = (const float*)d_in[0];
  const float* que   = (const float*)d_in[1];
  const float* cmask = (const float*)d_in[2];
  const float* qmask = (const float*)d_in[3];
  const float* ln_g  = (const float*)d_in[4];
  const float* ln_b  = (const float*)d_in[5];
  const float* dw_w  = (const float*)d_in[6];
  const float* dw_b  = (const float*)d_in[7];
  const float* pw_w  = (const float*)d_in[8];
  const float* pw_b  = (const float*)d_in[9];
  const float* Wq    = (const float*)d_in[10];
  const float* bq    = (const float*)d_in[11];
  const float* Wk    = (const float*)d_in[12];
  const float* bk    = (const float*)d_in[13];
  const float* Wv    = (const float*)d_in[14];
  const float* bv    = (const float*)d_in[15];
  const float* Wo    = (const float*)d_in[16];
  const float* bo    = (const float*)d_in[17];
  const float* Wfc   = (const float*)d_in[18];
  const float* bfc   = (const float*)d_in[19];
  const float* cq_wc = (const float*)d_in[20];
  const float* cq_wq = (const float*)d_in[21];
  const float* cq_wm = (const float*)d_in[22];
  const float* cq_b  = (const float*)d_in[23];
  float* out = (float*)d_out;
  float* ws = (float*)d_ws;

  float* Cb   = ws;
  float* Qb   = Cb + SZ_C;
  float* t1C  = Qb + SZ_Q;
  float* t1Q  = t1C + SZ_C;
  float* t2C  = t1Q + SZ_Q;
  float* t2Q  = t2C + SZ_C;
  float* t3C  = t2Q + SZ_Q;
  float* t3Q  = t3C + SZ_C;
  float* t4C  = t3Q + SZ_Q;
  float* t4Q  = t4C + SZ_C;
  float* mu0  = t4Q + SZ_Q;
  float* inv0 = mu0 + SSTAT;
  float* mu1  = inv0 + SSTAT;
  float* inv1 = mu1 + SSTAT;
  float* Wcan = inv1 + SSTAT;

  k_transposeW<<<(9 * 16384 + 255) / 256, 256, 0, stream>>>(pw_w, Wo, Wfc, Wq, Wk, Wv, Wcan);
  k_pestats<<<512, 256, 0, stream>>>(ctx, que, Cb, Qb, mu0, inv0);

  for (int i = 0; i < NC; ++i) {
    const float* inC = (i & 1) ? t1C : Cb;
    const float* inQ = (i & 1) ? t1Q : Qb;
    float* oC = (i & 1) ? Cb : t1C;
    float* oQ = (i & 1) ? Qb : t1Q;
    const float* mI = (i & 1) ? mu1 : mu0;
    const float* iI = (i & 1) ? inv1 : inv0;
    float* mO = (i & 1) ? mu0 : mu1;
    float* iO = (i & 1) ? inv0 : inv1;
    k_convgemm<<<512, 256, 0, stream>>>(inC, inQ, oC, oQ,
                                        Wcan + (size_t)i * 16384, pw_b + (size_t)i * DD,
                                        dw_w + (size_t)i * DD * KW, dw_b + (size_t)i * DD,
                                        mI, iI, mO, iO, ln_g, ln_b);
  }
  k_gemm_qkv<<<1536, 256, 0, stream>>>(Cb, Qb, t1C, t1Q, t2C, t2Q, t3C, t3Q,
                                       Wcan, bq, bk, bv, mu0, inv0, ln_g, ln_b);
  k_attn2<<<1536, 256, 0, stream>>>(t1C, t2C, t3C, t1Q, t2Q, t3Q, cmask, qmask, t4C, t4Q);
  k_gemm64<0, 1, 1><<<512, 256, 0, stream>>>(t4C, t4Q, Cb, Qb, Wcan + 4 * 16384, bo,
                                             mu0, inv0, mu1, inv1, ln_g, ln_b);
  k_gemm64<1, 1, 0><<<512, 256, 0, stream>>>(Cb, Qb, Cb, Qb, Wcan + 5 * 16384, bfc,
                                             mu1, inv1, mu0, inv0, ln_g, ln_b);

  // ---- context-query attention ----
  float* C2  = t1C;
  float* Q2  = t1Q;
  float* S   = t2C;
  float* Sr  = t2C + 1638400;
  float* Scb = t3C;
  float* Uu  = t2Q;
  float* cd  = t3Q;
  float* qd  = t4Q;

  k_prep<<<3953, 256, 0, stream>>>(Cb, Qb, C2, Q2, cq_wc, cq_wq, cd, qd);
  k_S<<<(BB * NN * MM + 255) / 256, 256, 0, stream>>>(C2, Q2, cd, qd, cq_wm, cq_b, S);
  k_smax<<<BB * MM + BB * NN, 64, 0, stream>>>(S, Sr, Scb, cmask, qmask);
  k_U<<<(BB * MM * 32 + 255) / 256, 256, 0, stream>>>(Scb, C2, Uu);
  k_ABtF<<<448, 256, 0, stream>>>(Sr, Q2, Uu, C2, out);
}